// Round 1
// baseline (8172.510 us; speedup 1.0000x reference)
//
#include <hip/hip_runtime.h>
#include <math.h>

#define BATCH 16
#define NPTS  4096
#define NCTR  512
#define STEM  128
#define TOK   256
#define D_IN  155   // 128 + 3 + 24
#define D_TOK 992   // 128 + 3*256 + 96

// exact, non-contracted squared distance (a - b), summed left-to-right,
// to match numpy/XLA-CPU f32 rounding (no FMA).
__device__ __forceinline__ float sq3(float ax, float ay, float az,
                                     float bx, float by, float bz) {
    float dx = __fsub_rn(ax, bx);
    float dy = __fsub_rn(ay, by);
    float dz = __fsub_rn(az, bz);
    float d = __fmul_rn(dx, dx);
    d = __fadd_rn(d, __fmul_rn(dy, dy));
    d = __fadd_rn(d, __fmul_rn(dz, dz));
    return d;
}

// ---------------- FPS: one block per batch, 256 threads, 16 pts/thread ----
__global__ __launch_bounds__(256) void fps_kernel(const float* __restrict__ xyz,
                                                  int* __restrict__ center_idx,
                                                  float* __restrict__ pc_ws,
                                                  float* __restrict__ pc_out) {
    int b = blockIdx.x;
    int t = threadIdx.x;
    const float* X = xyz + (size_t)b * NPTS * 3;
    float px[16], py[16], pz[16], dist[16];
#pragma unroll
    for (int j = 0; j < 16; ++j) {
        int i = t + 256 * j;
        px[j] = X[i * 3 + 0];
        py[j] = X[i * 3 + 1];
        pz[j] = X[i * 3 + 2];
        dist[j] = 1e10f;
    }
    __shared__ float sc[3];
    __shared__ int sfar;
    __shared__ float swv[4];
    __shared__ int swi[4];
    int far = 0;
    for (int s = 0; s < NCTR; ++s) {
        if (t == 0) {
            float cx = X[far * 3], cy = X[far * 3 + 1], cz = X[far * 3 + 2];
            sc[0] = cx; sc[1] = cy; sc[2] = cz;
            center_idx[b * NCTR + s] = far;
            size_t po = (size_t)(b * NCTR + s) * 3;
            pc_ws[po] = cx; pc_ws[po + 1] = cy; pc_ws[po + 2] = cz;
            pc_out[po] = cx; pc_out[po + 1] = cy; pc_out[po + 2] = cz;
        }
        __syncthreads();
        float cx = sc[0], cy = sc[1], cz = sc[2];
        float bv = -1.0f;
        int bi = 0;
#pragma unroll
        for (int j = 0; j < 16; ++j) {
            float d = sq3(px[j], py[j], pz[j], cx, cy, cz);
            float nd = fminf(dist[j], d);
            dist[j] = nd;
            // strictly greater: keeps earliest index within this thread
            if (nd > bv) { bv = nd; bi = t + 256 * j; }
        }
#pragma unroll
        for (int off = 32; off >= 1; off >>= 1) {
            float ov = __shfl_xor(bv, off, 64);
            int   oi = __shfl_xor(bi, off, 64);
            if (ov > bv || (ov == bv && oi < bi)) { bv = ov; bi = oi; }
        }
        if ((t & 63) == 0) { swv[t >> 6] = bv; swi[t >> 6] = bi; }
        __syncthreads();
        if (t == 0) {
            for (int w2 = 1; w2 < 4; ++w2) {
                float ov = swv[w2]; int oi = swi[w2];
                if (ov > bv || (ov == bv && oi < bi)) { bv = ov; bi = oi; }
            }
            sfar = bi;
        }
        __syncthreads();
        far = sfar;
    }
}

// ---------------- Ball query: one wave per center, ascending-index scan ----
template <int K>
__global__ __launch_bounds__(256) void ballq_kernel(const float* __restrict__ xyz,
                                                    const float* __restrict__ pc,
                                                    int* __restrict__ nbr,
                                                    float rr) {
    int cid = blockIdx.x * 4 + (threadIdx.x >> 6);  // b*NCTR + c
    int lane = threadIdx.x & 63;
    int b = cid >> 9;
    const float* X = xyz + (size_t)b * NPTS * 3;
    float cx = pc[(size_t)cid * 3 + 0];
    float cy = pc[(size_t)cid * 3 + 1];
    float cz = pc[(size_t)cid * 3 + 2];
    int cnt = 0, first = 0;
    bool have_first = false;
    long long base = (long long)cid * K;
    for (int it = 0; it < NPTS / 64; ++it) {
        int i = it * 64 + lane;
        float d = sq3(cx, cy, cz, X[i * 3], X[i * 3 + 1], X[i * 3 + 2]);
        bool ok = d <= rr;  // matches !(sqr > r*r)
        unsigned long long mask = __ballot(ok);
        if (!have_first && mask) {
            first = it * 64 + (int)__builtin_ctzll(mask);
            have_first = true;
        }
        int pos = cnt + (int)__popcll(mask & ((1ull << lane) - 1ull));
        if (ok && pos < K) nbr[base + pos] = i;
        cnt += (int)__popcll(mask);
        if (cnt >= K) break;
    }
    int fill = cnt < K ? cnt : K;
    for (int j = fill + lane; j < K; j += 64) nbr[base + j] = first;
}

// ---------------- Per-scale grouped MLP: one block per (b, center) --------
template <int K>
__global__ __launch_bounds__(256) void scale_kernel(
    const float* __restrict__ xyz, const float* __restrict__ pf,
    const float* __restrict__ W1, const float* __restrict__ b1,
    const float* __restrict__ g1, const float* __restrict__ be1,
    const float* __restrict__ W2, const float* __restrict__ b2,
    const float* __restrict__ g2, const float* __restrict__ be2,
    const int* __restrict__ nbr, const float* __restrict__ pc,
    float* __restrict__ outf) {
    int bc = blockIdx.x;
    int b = bc >> 9;
    int t = threadIdx.x;
    int w = t >> 6, lane = t & 63;
    __shared__ __align__(16) float gin[K][156];  // row stride 624B (16-mult)
    __shared__ __align__(16) float h[K][260];    // row stride 1040B (16-mult)
    __shared__ float smean[K], srstd[K];
    __shared__ int snb[K];
    __shared__ float sctr[3];
    if (t < K) snb[t] = nbr[(size_t)bc * K + t];
    if (t >= 64 && t < 67) sctr[t - 64] = pc[(size_t)bc * 3 + (t - 64)];
    __syncthreads();
    float cx = sctr[0], cy = sctr[1], cz = sctr[2];
    const float* Xb = xyz + (size_t)b * NPTS * 3;
    // build gin: wave w handles rows r = w, w+4, ...
    for (int r = w; r < K; r += 4) {
        int n = snb[r];
        const float* src = pf + ((size_t)b * NPTS + n) * STEM;
        gin[r][lane] = src[lane];
        gin[r][64 + lane] = src[64 + lane];
        if (lane < 3) {
            float c = (lane == 0) ? cx : ((lane == 1) ? cy : cz);
            gin[r][128 + lane] = __fsub_rn(Xb[(size_t)n * 3 + lane], c);
        }
        if (lane < 24) {
            int axis = lane >> 3;
            int rem = lane & 7;
            float c = (axis == 0) ? cx : ((axis == 1) ? cy : cz);
            float rel = __fsub_rn(Xb[(size_t)n * 3 + axis], c);
            int fi = (rem < 4) ? rem : rem - 4;
            float fr = expf(__fdiv_rn(-logf(10000.0f) * (float)fi, 3.0f));
            float ang = rel * fr;
            gin[r][131 + lane] = (rem < 4) ? sinf(ang) : cosf(ang);
        }
        if (lane == 63) gin[r][155] = 0.0f;  // zero pad (w3 guard below too)
    }
    __syncthreads();
    // ---- MLP1: x(K x 155) @ W1(155 x 256); thread t owns column t ----
    float acc[K];
    {
        float bias = b1[t];
#pragma unroll
        for (int r = 0; r < K; ++r) acc[r] = bias;
    }
    for (int i = 0; i < 156; i += 4) {
        float w0 = W1[(i + 0) * TOK + t];
        float w1 = W1[(i + 1) * TOK + t];
        float w2 = W1[(i + 2) * TOK + t];
        float w3 = (i + 3 < D_IN) ? W1[(i + 3) * TOK + t] : 0.0f;
#pragma unroll
        for (int r = 0; r < K; ++r) {
            const float4 g = *reinterpret_cast<const float4*>(&gin[r][i]);
            acc[r] = fmaf(g.x, w0, acc[r]);
            acc[r] = fmaf(g.y, w1, acc[r]);
            acc[r] = fmaf(g.z, w2, acc[r]);
            acc[r] = fmaf(g.w, w3, acc[r]);
        }
    }
    // ---- LN1 stats ----
#pragma unroll
    for (int r = 0; r < K; ++r) h[r][t] = acc[r];
    __syncthreads();
    if (t < K) {
        float s = 0.f, ss = 0.f;
        for (int i = 0; i < TOK; ++i) { float v = h[t][i]; s += v; ss = fmaf(v, v, ss); }
        float m = s * (1.0f / 256.0f);
        float var = ss * (1.0f / 256.0f) - m * m;
        smean[t] = m;
        srstd[t] = rsqrtf(var + 1e-5f);
    }
    __syncthreads();
    {
        float gt = g1[t], bt = be1[t];
#pragma unroll
        for (int r = 0; r < K; ++r) {
            float v = (acc[r] - smean[r]) * srstd[r] * gt + bt;
            v = 0.5f * v * (1.0f + erff(v * 0.70710678118654752f));  // exact gelu
            h[r][t] = v;
        }
    }
    __syncthreads();
    // ---- MLP2: h(K x 256) @ W2(256 x 256) ----
    float acc2[K];
    {
        float bias = b2[t];
#pragma unroll
        for (int r = 0; r < K; ++r) acc2[r] = bias;
    }
    for (int i = 0; i < TOK; i += 4) {
        float w0 = W2[(i + 0) * TOK + t];
        float w1 = W2[(i + 1) * TOK + t];
        float w2 = W2[(i + 2) * TOK + t];
        float w3 = W2[(i + 3) * TOK + t];
#pragma unroll
        for (int r = 0; r < K; ++r) {
            const float4 g = *reinterpret_cast<const float4*>(&h[r][i]);
            acc2[r] = fmaf(g.x, w0, acc2[r]);
            acc2[r] = fmaf(g.y, w1, acc2[r]);
            acc2[r] = fmaf(g.z, w2, acc2[r]);
            acc2[r] = fmaf(g.w, w3, acc2[r]);
        }
    }
    __syncthreads();  // all reads of h done
#pragma unroll
    for (int r = 0; r < K; ++r) h[r][t] = acc2[r];
    __syncthreads();
    if (t < K) {
        float s = 0.f, ss = 0.f;
        for (int i = 0; i < TOK; ++i) { float v = h[t][i]; s += v; ss = fmaf(v, v, ss); }
        float m = s * (1.0f / 256.0f);
        float var = ss * (1.0f / 256.0f) - m * m;
        smean[t] = m;
        srstd[t] = rsqrtf(var + 1e-5f);
    }
    __syncthreads();
    {
        float gt = g2[t], bt = be2[t];
        float mx = -3.4e38f;
#pragma unroll
        for (int r = 0; r < K; ++r) {
            float v = (acc2[r] - smean[r]) * srstd[r] * gt + bt;
            mx = fmaxf(mx, v);
        }
        outf[(size_t)bc * TOK + t] = mx;
    }
}

// ---------------- Token MLP: one block per (b, center) --------------------
__global__ __launch_bounds__(256) void token_kernel(
    const float* __restrict__ pf,
    const float* __restrict__ tW1, const float* __restrict__ tb1,
    const float* __restrict__ tg1, const float* __restrict__ tbe1,
    const float* __restrict__ tW2, const float* __restrict__ tb2,
    const float* __restrict__ tg2, const float* __restrict__ tbe2,
    const int* __restrict__ center_idx, const float* __restrict__ pc,
    const float* __restrict__ sf0, const float* __restrict__ sf1,
    const float* __restrict__ sf2, float* __restrict__ out) {
    int bc = blockIdx.x;
    int b = bc >> 9;
    int t = threadIdx.x;
    __shared__ __align__(16) float tin[D_TOK];
    __shared__ float hh[TOK];
    __shared__ float red[8];
    int cidx = center_idx[bc];
    if (t < STEM) tin[t] = pf[((size_t)b * NPTS + cidx) * STEM + t];
    tin[128 + t] = sf0[(size_t)bc * TOK + t];
    tin[384 + t] = sf1[(size_t)bc * TOK + t];
    tin[640 + t] = sf2[(size_t)bc * TOK + t];
    if (t < 96) {
        int axis = t >> 5;
        int rem = t & 31;
        float c = pc[(size_t)bc * 3 + axis];
        int fi = (rem < 16) ? rem : rem - 16;
        float fr = expf(__fdiv_rn(-logf(10000.0f) * (float)fi, 15.0f));
        float ang = c * fr;
        tin[896 + t] = (rem < 16) ? sinf(ang) : cosf(ang);
    }
    __syncthreads();
    float acc = tb1[t];
    for (int i = 0; i < D_TOK; i += 4) {
        float4 x = *reinterpret_cast<const float4*>(&tin[i]);
        acc = fmaf(x.x, tW1[(i + 0) * TOK + t], acc);
        acc = fmaf(x.y, tW1[(i + 1) * TOK + t], acc);
        acc = fmaf(x.z, tW1[(i + 2) * TOK + t], acc);
        acc = fmaf(x.w, tW1[(i + 3) * TOK + t], acc);
    }
    int w = t >> 6, lane = t & 63;
    float s = acc, ss = acc * acc;
#pragma unroll
    for (int off = 32; off >= 1; off >>= 1) {
        s += __shfl_xor(s, off, 64);
        ss += __shfl_xor(ss, off, 64);
    }
    if (lane == 0) { red[w * 2] = s; red[w * 2 + 1] = ss; }
    __syncthreads();
    float S4 = red[0] + red[2] + red[4] + red[6];
    float SS4 = red[1] + red[3] + red[5] + red[7];
    float m = S4 * (1.0f / 256.0f);
    float var = SS4 * (1.0f / 256.0f) - m * m;
    float rs = rsqrtf(var + 1e-5f);
    float v = (acc - m) * rs * tg1[t] + tbe1[t];
    v = 0.5f * v * (1.0f + erff(v * 0.70710678118654752f));
    hh[t] = v;
    __syncthreads();
    float acc2 = tb2[t];
    for (int i = 0; i < TOK; i += 4) {
        float4 x = *reinterpret_cast<const float4*>(&hh[i]);
        acc2 = fmaf(x.x, tW2[(i + 0) * TOK + t], acc2);
        acc2 = fmaf(x.y, tW2[(i + 1) * TOK + t], acc2);
        acc2 = fmaf(x.z, tW2[(i + 2) * TOK + t], acc2);
        acc2 = fmaf(x.w, tW2[(i + 3) * TOK + t], acc2);
    }
    float s2 = acc2, ss2 = acc2 * acc2;
#pragma unroll
    for (int off = 32; off >= 1; off >>= 1) {
        s2 += __shfl_xor(s2, off, 64);
        ss2 += __shfl_xor(ss2, off, 64);
    }
    __syncthreads();  // protect red from previous reads
    if (lane == 0) { red[w * 2] = s2; red[w * 2 + 1] = ss2; }
    __syncthreads();
    float S42 = red[0] + red[2] + red[4] + red[6];
    float SS42 = red[1] + red[3] + red[5] + red[7];
    float m2 = S42 * (1.0f / 256.0f);
    float var2 = SS42 * (1.0f / 256.0f) - m2 * m2;
    float rs2 = rsqrtf(var2 + 1e-5f);
    float v2 = (acc2 - m2) * rs2 * tg2[t] + tbe2[t];
    out[(size_t)bc * TOK + t] = v2;
}

extern "C" void kernel_launch(void* const* d_in, const int* in_sizes, int n_in,
                              void* d_out, int out_size, void* d_ws, size_t ws_size,
                              hipStream_t stream) {
    const float* xyz  = (const float*)d_in[0];
    const float* pf   = (const float*)d_in[1];
    const float* sW1  = (const float*)d_in[2];
    const float* sb1  = (const float*)d_in[3];
    const float* sg1  = (const float*)d_in[4];
    const float* sbe1 = (const float*)d_in[5];
    const float* sW2  = (const float*)d_in[6];
    const float* sb2  = (const float*)d_in[7];
    const float* sg2  = (const float*)d_in[8];
    const float* sbe2 = (const float*)d_in[9];
    const float* tW1  = (const float*)d_in[10];
    const float* tb1  = (const float*)d_in[11];
    const float* tg1  = (const float*)d_in[12];
    const float* tbe1 = (const float*)d_in[13];
    const float* tW2  = (const float*)d_in[14];
    const float* tb2  = (const float*)d_in[15];
    const float* tg2  = (const float*)d_in[16];
    const float* tbe2 = (const float*)d_in[17];

    float* out_tok = (float*)d_out;
    float* out_pc  = out_tok + (size_t)BATCH * NCTR * TOK;

    char* ws = (char*)d_ws;
    int* center_idx = (int*)ws;   ws += (size_t)BATCH * NCTR * 4;
    float* pc_ws    = (float*)ws; ws += (size_t)BATCH * NCTR * 3 * 4;
    int* nbr0       = (int*)ws;   ws += (size_t)BATCH * NCTR * 16 * 4;
    int* nbr1       = (int*)ws;   ws += (size_t)BATCH * NCTR * 32 * 4;
    int* nbr2       = (int*)ws;   ws += (size_t)BATCH * NCTR * 64 * 4;
    float* sf0      = (float*)ws; ws += (size_t)BATCH * NCTR * TOK * 4;
    float* sf1      = (float*)ws; ws += (size_t)BATCH * NCTR * TOK * 4;
    float* sf2      = (float*)ws; ws += (size_t)BATCH * NCTR * TOK * 4;

    fps_kernel<<<BATCH, 256, 0, stream>>>(xyz, center_idx, pc_ws, out_pc);

    ballq_kernel<16><<<BATCH * NCTR / 4, 256, 0, stream>>>(xyz, pc_ws, nbr0, (float)(0.1 * 0.1));
    ballq_kernel<32><<<BATCH * NCTR / 4, 256, 0, stream>>>(xyz, pc_ws, nbr1, (float)(0.2 * 0.2));
    ballq_kernel<64><<<BATCH * NCTR / 4, 256, 0, stream>>>(xyz, pc_ws, nbr2, (float)(0.4 * 0.4));

    scale_kernel<16><<<BATCH * NCTR, 256, 0, stream>>>(
        xyz, pf, sW1 + 0 * D_IN * TOK, sb1 + 0 * TOK, sg1 + 0 * TOK, sbe1 + 0 * TOK,
        sW2 + 0 * TOK * TOK, sb2 + 0 * TOK, sg2 + 0 * TOK, sbe2 + 0 * TOK,
        nbr0, pc_ws, sf0);
    scale_kernel<32><<<BATCH * NCTR, 256, 0, stream>>>(
        xyz, pf, sW1 + 1 * D_IN * TOK, sb1 + 1 * TOK, sg1 + 1 * TOK, sbe1 + 1 * TOK,
        sW2 + 1 * TOK * TOK, sb2 + 1 * TOK, sg2 + 1 * TOK, sbe2 + 1 * TOK,
        nbr1, pc_ws, sf1);
    scale_kernel<64><<<BATCH * NCTR, 256, 0, stream>>>(
        xyz, pf, sW1 + 2 * D_IN * TOK, sb1 + 2 * TOK, sg1 + 2 * TOK, sbe1 + 2 * TOK,
        sW2 + 2 * TOK * TOK, sb2 + 2 * TOK, sg2 + 2 * TOK, sbe2 + 2 * TOK,
        nbr2, pc_ws, sf2);

    token_kernel<<<BATCH * NCTR, 256, 0, stream>>>(
        pf, tW1, tb1, tg1, tbe1, tW2, tb2, tg2, tbe2,
        center_idx, pc_ws, sf0, sf1, sf2, out_tok);
}

// Round 2
// 3268.512 us; speedup vs baseline: 2.5004x; 2.5004x over previous
//
#include <hip/hip_runtime.h>
#include <math.h>

#define BATCH 16
#define NPTS  4096
#define NCTR  512
#define STEM  128
#define TOK   256
#define D_IN  155   // 128 + 3 + 24
#define D_TOK 992   // 128 + 3*256 + 96

typedef short s16x8 __attribute__((ext_vector_type(8)));
typedef float f32x4 __attribute__((ext_vector_type(4)));

__device__ __forceinline__ unsigned short f2bf(float f) {
    unsigned u = __float_as_uint(f);
    u += 0x7FFF + ((u >> 16) & 1);   // round-to-nearest-even
    return (unsigned short)(u >> 16);
}
__device__ __forceinline__ float bf2f(unsigned short b) {
    return __uint_as_float(((unsigned)b) << 16);
}

// exact, non-contracted squared distance to match numpy f32 rounding
__device__ __forceinline__ float sq3(float ax, float ay, float az,
                                     float bx, float by, float bz) {
    float dx = __fsub_rn(ax, bx);
    float dy = __fsub_rn(ay, by);
    float dz = __fsub_rn(az, bz);
    float d = __fmul_rn(dx, dx);
    d = __fadd_rn(d, __fmul_rn(dy, dy));
    d = __fadd_rn(d, __fmul_rn(dz, dz));
    return d;
}

// ---------------- FPS: one block per batch (unchanged, index-exact) -------
__global__ __launch_bounds__(256) void fps_kernel(const float* __restrict__ xyz,
                                                  int* __restrict__ center_idx,
                                                  float* __restrict__ pc_ws,
                                                  float* __restrict__ pc_out) {
    int b = blockIdx.x;
    int t = threadIdx.x;
    const float* X = xyz + (size_t)b * NPTS * 3;
    float px[16], py[16], pz[16], dist[16];
#pragma unroll
    for (int j = 0; j < 16; ++j) {
        int i = t + 256 * j;
        px[j] = X[i * 3 + 0];
        py[j] = X[i * 3 + 1];
        pz[j] = X[i * 3 + 2];
        dist[j] = 1e10f;
    }
    __shared__ float sc[3];
    __shared__ int sfar;
    __shared__ float swv[4];
    __shared__ int swi[4];
    int far = 0;
    for (int s = 0; s < NCTR; ++s) {
        if (t == 0) {
            float cx = X[far * 3], cy = X[far * 3 + 1], cz = X[far * 3 + 2];
            sc[0] = cx; sc[1] = cy; sc[2] = cz;
            center_idx[b * NCTR + s] = far;
            size_t po = (size_t)(b * NCTR + s) * 3;
            pc_ws[po] = cx; pc_ws[po + 1] = cy; pc_ws[po + 2] = cz;
            pc_out[po] = cx; pc_out[po + 1] = cy; pc_out[po + 2] = cz;
        }
        __syncthreads();
        float cx = sc[0], cy = sc[1], cz = sc[2];
        float bv = -1.0f;
        int bi = 0;
#pragma unroll
        for (int j = 0; j < 16; ++j) {
            float d = sq3(px[j], py[j], pz[j], cx, cy, cz);
            float nd = fminf(dist[j], d);
            dist[j] = nd;
            if (nd > bv) { bv = nd; bi = t + 256 * j; }
        }
#pragma unroll
        for (int off = 32; off >= 1; off >>= 1) {
            float ov = __shfl_xor(bv, off, 64);
            int   oi = __shfl_xor(bi, off, 64);
            if (ov > bv || (ov == bv && oi < bi)) { bv = ov; bi = oi; }
        }
        if ((t & 63) == 0) { swv[t >> 6] = bv; swi[t >> 6] = bi; }
        __syncthreads();
        if (t == 0) {
            for (int w2 = 1; w2 < 4; ++w2) {
                float ov = swv[w2]; int oi = swi[w2];
                if (ov > bv || (ov == bv && oi < bi)) { bv = ov; bi = oi; }
            }
            sfar = bi;
        }
        __syncthreads();
        far = sfar;
    }
}

// ---------------- Ball query (unchanged) ----------------------------------
template <int K>
__global__ __launch_bounds__(256) void ballq_kernel(const float* __restrict__ xyz,
                                                    const float* __restrict__ pc,
                                                    int* __restrict__ nbr,
                                                    float rr) {
    int cid = blockIdx.x * 4 + (threadIdx.x >> 6);
    int lane = threadIdx.x & 63;
    int b = cid >> 9;
    const float* X = xyz + (size_t)b * NPTS * 3;
    float cx = pc[(size_t)cid * 3 + 0];
    float cy = pc[(size_t)cid * 3 + 1];
    float cz = pc[(size_t)cid * 3 + 2];
    int cnt = 0, first = 0;
    bool have_first = false;
    long long base = (long long)cid * K;
    for (int it = 0; it < NPTS / 64; ++it) {
        int i = it * 64 + lane;
        float d = sq3(cx, cy, cz, X[i * 3], X[i * 3 + 1], X[i * 3 + 2]);
        bool ok = d <= rr;
        unsigned long long mask = __ballot(ok);
        if (!have_first && mask) {
            first = it * 64 + (int)__builtin_ctzll(mask);
            have_first = true;
        }
        int pos = cnt + (int)__popcll(mask & ((1ull << lane) - 1ull));
        if (ok && pos < K) nbr[base + pos] = i;
        cnt += (int)__popcll(mask);
        if (cnt >= K) break;
    }
    int fill = cnt < K ? cnt : K;
    for (int j = fill + lane; j < K; j += 64) nbr[base + j] = first;
}

// ---------------- Weight pack: f32 row-major -> hi/lo bf16 MFMA B-frags ----
// frag index f = ct*KS + ks; lane l holds B[k0 + (l>>4)*8 + j][ct*16 + (l&15)]
// stored as 8 hi shorts then 8 lo shorts (32B per lane).
__global__ __launch_bounds__(256) void pack_w(const float* __restrict__ Wbase,
                                              unsigned short* __restrict__ out,
                                              int Kdim, int KS) {
    int s = blockIdx.y;
    const float* W = Wbase + (size_t)s * Kdim * TOK;
    unsigned short* o = out + (size_t)s * 16 * KS * 64 * 16;
    int tid = blockIdx.x * 256 + threadIdx.x;
    if (tid >= 16 * KS * 64) return;
    int lane = tid & 63;
    int frag = tid >> 6;
    int ks = frag % KS;
    int ct = frag / KS;
    int col = ct * 16 + (lane & 15);
    int k0 = ks * 32 + (lane >> 4) * 8;
    unsigned short* dst = o + (size_t)tid * 16;
#pragma unroll
    for (int j = 0; j < 8; ++j) {
        int k = k0 + j;
        float v = (k < Kdim) ? W[(size_t)k * TOK + col] : 0.0f;
        unsigned short h = f2bf(v);
        dst[j] = h;
        dst[8 + j] = f2bf(v - bf2f(h));
    }
}

// ---------------- Per-scale grouped MLP via bf16x3 MFMA --------------------
// Block = 4 waves x 32 rows = 128 neighbor rows. Wave-private.
template <int K>
__global__ __launch_bounds__(256, 2) void scale_mfma(
    const float* __restrict__ xyz, const float* __restrict__ pf,
    const unsigned short* __restrict__ pk1, const float* __restrict__ b1,
    const float* __restrict__ g1, const float* __restrict__ be1,
    const unsigned short* __restrict__ pk2, const float* __restrict__ b2,
    const float* __restrict__ g2, const float* __restrict__ be2,
    const int* __restrict__ nbr, const float* __restrict__ pc,
    float* __restrict__ outf) {
    __shared__ __align__(16) float hbuf[4][32][68];  // wave-private h chunk
    __shared__ float maxbuf[4][256];                 // K=64 cross-wave max
    const int w = threadIdx.x >> 6, l = threadIdx.x & 63;
    const int lg = l >> 4, li = l & 15;
    const int rowbase = blockIdx.x * 128 + w * 32;

    // per row-block (rb): row = rowbase + rb*16 + li
    int nb[2];
    float rel[2][3];
#pragma unroll
    for (int rb = 0; rb < 2; ++rb) {
        int row = rowbase + rb * 16 + li;
        int c = row / K;
        int b = c >> 9;
        int n = nbr[row];
        nb[rb] = (b << 12) + n;
        const float* X = xyz + ((size_t)nb[rb]) * 3;
        const float* C = pc + (size_t)c * 3;
        rel[rb][0] = __fsub_rn(X[0], C[0]);
        rel[rb][1] = __fsub_rn(X[1], C[1]);
        rel[rb][2] = __fsub_rn(X[2], C[2]);
    }

    // ---------------- MLP1: [32 x 160] @ [160 x 256] (bf16x3) -------------
    f32x4 acc[2][16];
#pragma unroll
    for (int rb = 0; rb < 2; ++rb)
#pragma unroll
        for (int t = 0; t < 16; ++t) acc[rb][t] = (f32x4){0.f, 0.f, 0.f, 0.f};

#pragma unroll
    for (int ks = 0; ks < 5; ++ks) {
        s16x8 Ah[2], Al[2];
#pragma unroll
        for (int rb = 0; rb < 2; ++rb) {
            float v[8];
            if (ks < 4) {
                const float* src = pf + (size_t)nb[rb] * STEM + ks * 32 + lg * 8;
                float4 f0 = *(const float4*)src;
                float4 f1 = *(const float4*)(src + 4);
                v[0] = f0.x; v[1] = f0.y; v[2] = f0.z; v[3] = f0.w;
                v[4] = f1.x; v[5] = f1.y; v[6] = f1.z; v[7] = f1.w;
            } else {
#pragma unroll
                for (int j = 0; j < 8; ++j) {
                    int ch = lg * 8 + j;  // feature 128+ch
                    float val = 0.0f;
                    if (ch < 3) {
                        val = rel[rb][ch];
                    } else if (ch < 27) {
                        int rem = ch - 3;
                        int axis = rem >> 3, r8 = rem & 7;
                        int fi = (r8 < 4) ? r8 : r8 - 4;
                        float fr = expf(__fdiv_rn(-logf(10000.0f) * (float)fi, 3.0f));
                        float ang = rel[rb][axis] * fr;
                        val = (r8 < 4) ? sinf(ang) : cosf(ang);
                    }
                    v[j] = val;
                }
            }
#pragma unroll
            for (int j = 0; j < 8; ++j) {
                unsigned short h = f2bf(v[j]);
                Ah[rb][j] = (short)h;
                Al[rb][j] = (short)f2bf(v[j] - bf2f(h));
            }
        }
#pragma unroll
        for (int ct = 0; ct < 16; ++ct) {
            const s16x8* bp = (const s16x8*)(pk1 + (((size_t)ct * 5 + ks) * 64 + l) * 16);
            s16x8 Bh = bp[0], Bl = bp[1];
#pragma unroll
            for (int rb = 0; rb < 2; ++rb) {
                acc[rb][ct] = __builtin_amdgcn_mfma_f32_16x16x32_bf16(Ah[rb], Bh, acc[rb][ct], 0, 0, 0);
                acc[rb][ct] = __builtin_amdgcn_mfma_f32_16x16x32_bf16(Ah[rb], Bl, acc[rb][ct], 0, 0, 0);
                acc[rb][ct] = __builtin_amdgcn_mfma_f32_16x16x32_bf16(Al[rb], Bh, acc[rb][ct], 0, 0, 0);
            }
        }
    }

    // ---------------- bias + LN1 + GELU (stats via 16-lane shfl) ----------
    float b1v[16], g1v[16], be1v[16];
#pragma unroll
    for (int t = 0; t < 16; ++t) {
        int col = t * 16 + li;
        b1v[t] = b1[col]; g1v[t] = g1[col]; be1v[t] = be1[col];
    }
#pragma unroll
    for (int rb = 0; rb < 2; ++rb) {
#pragma unroll
        for (int reg = 0; reg < 4; ++reg) {
            float s = 0.f, ss = 0.f;
#pragma unroll
            for (int t = 0; t < 16; ++t) {
                float x = acc[rb][t][reg] + b1v[t];
                s += x; ss = fmaf(x, x, ss);
            }
#pragma unroll
            for (int m = 1; m <= 8; m <<= 1) {
                s += __shfl_xor(s, m, 64);
                ss += __shfl_xor(ss, m, 64);
            }
            float mean = s * (1.0f / 256.0f);
            float var = ss * (1.0f / 256.0f) - mean * mean;
            float rs = rsqrtf(var + 1e-5f);
#pragma unroll
            for (int t = 0; t < 16; ++t) {
                float x = acc[rb][t][reg] + b1v[t];
                float vv = (x - mean) * rs * g1v[t] + be1v[t];
                acc[rb][t][reg] = 0.5f * vv * (1.0f + erff(vv * 0.70710678118654752f));
            }
        }
    }

    // ---------------- MLP2: [32 x 256] @ [256 x 256] (bf16x3) -------------
    // transpose h through a 64-col wave-private LDS chunk
    f32x4 acc2[2][16];
#pragma unroll
    for (int rb = 0; rb < 2; ++rb)
#pragma unroll
        for (int t = 0; t < 16; ++t) acc2[rb][t] = (f32x4){0.f, 0.f, 0.f, 0.f};

#pragma unroll
    for (int c = 0; c < 4; ++c) {
#pragma unroll
        for (int rb = 0; rb < 2; ++rb)
#pragma unroll
            for (int tl = 0; tl < 4; ++tl) {
                int t = 4 * c + tl;
#pragma unroll
                for (int reg = 0; reg < 4; ++reg)
                    hbuf[w][rb * 16 + lg * 4 + reg][tl * 16 + li] = acc[rb][t][reg];
            }
#pragma unroll
        for (int kl = 0; kl < 2; ++kl) {
            s16x8 Ah2[2], Al2[2];
#pragma unroll
            for (int rb = 0; rb < 2; ++rb) {
                const float* hp = &hbuf[w][rb * 16 + li][kl * 32 + lg * 8];
                float4 f0 = *(const float4*)hp;
                float4 f1 = *(const float4*)(hp + 4);
                float v[8] = {f0.x, f0.y, f0.z, f0.w, f1.x, f1.y, f1.z, f1.w};
#pragma unroll
                for (int j = 0; j < 8; ++j) {
                    unsigned short h = f2bf(v[j]);
                    Ah2[rb][j] = (short)h;
                    Al2[rb][j] = (short)f2bf(v[j] - bf2f(h));
                }
            }
            int ksg = c * 2 + kl;
#pragma unroll
            for (int ct = 0; ct < 16; ++ct) {
                const s16x8* bp = (const s16x8*)(pk2 + (((size_t)ct * 8 + ksg) * 64 + l) * 16);
                s16x8 Bh = bp[0], Bl = bp[1];
#pragma unroll
                for (int rb = 0; rb < 2; ++rb) {
                    acc2[rb][ct] = __builtin_amdgcn_mfma_f32_16x16x32_bf16(Ah2[rb], Bh, acc2[rb][ct], 0, 0, 0);
                    acc2[rb][ct] = __builtin_amdgcn_mfma_f32_16x16x32_bf16(Ah2[rb], Bl, acc2[rb][ct], 0, 0, 0);
                    acc2[rb][ct] = __builtin_amdgcn_mfma_f32_16x16x32_bf16(Al2[rb], Bh, acc2[rb][ct], 0, 0, 0);
                }
            }
        }
    }

    // ---------------- bias + LN2 + max-pool --------------------------------
    float b2v[16], g2v[16], be2v[16];
#pragma unroll
    for (int t = 0; t < 16; ++t) {
        int col = t * 16 + li;
        b2v[t] = b2[col]; g2v[t] = g2[col]; be2v[t] = be2[col];
    }
    float mrb[2][16];
#pragma unroll
    for (int rb = 0; rb < 2; ++rb) {
#pragma unroll
        for (int reg = 0; reg < 4; ++reg) {
            float s = 0.f, ss = 0.f;
#pragma unroll
            for (int t = 0; t < 16; ++t) {
                float x = acc2[rb][t][reg] + b2v[t];
                s += x; ss = fmaf(x, x, ss);
            }
#pragma unroll
            for (int m = 1; m <= 8; m <<= 1) {
                s += __shfl_xor(s, m, 64);
                ss += __shfl_xor(ss, m, 64);
            }
            float mean = s * (1.0f / 256.0f);
            float var = ss * (1.0f / 256.0f) - mean * mean;
            float rs = rsqrtf(var + 1e-5f);
#pragma unroll
            for (int t = 0; t < 16; ++t) {
                float x = acc2[rb][t][reg] + b2v[t];
                acc2[rb][t][reg] = (x - mean) * rs * g2v[t] + be2v[t];
            }
        }
#pragma unroll
        for (int t = 0; t < 16; ++t) {
            float m = fmaxf(fmaxf(acc2[rb][t][0], acc2[rb][t][1]),
                            fmaxf(acc2[rb][t][2], acc2[rb][t][3]));
            m = fmaxf(m, __shfl_xor(m, 16, 64));
            m = fmaxf(m, __shfl_xor(m, 32, 64));
            mrb[rb][t] = m;  // max over the 16 rows of this rb
        }
    }

    if (K == 16) {
        if (lg == 0) {
#pragma unroll
            for (int rb = 0; rb < 2; ++rb) {
                int c = (rowbase + rb * 16) >> 4;
#pragma unroll
                for (int t = 0; t < 16; ++t)
                    outf[(size_t)c * TOK + t * 16 + li] = mrb[rb][t];
            }
        }
    } else if (K == 32) {
        if (lg == 0) {
            int c = rowbase >> 5;
#pragma unroll
            for (int t = 0; t < 16; ++t)
                outf[(size_t)c * TOK + t * 16 + li] = fmaxf(mrb[0][t], mrb[1][t]);
        }
    } else {  // K == 64: combine the two waves of each center via LDS
        if (lg == 0) {
#pragma unroll
            for (int t = 0; t < 16; ++t)
                maxbuf[w][t * 16 + li] = fmaxf(mrb[0][t], mrb[1][t]);
        }
        __syncthreads();
        if ((w & 1) == 0 && lg == 0) {
            int c = rowbase >> 6;
#pragma unroll
            for (int t = 0; t < 16; ++t) {
                int cc = t * 16 + li;
                outf[(size_t)c * TOK + cc] = fmaxf(maxbuf[w][cc], maxbuf[w + 1][cc]);
            }
        }
    }
}

// ---------------- Token MLP (unchanged, f32) -------------------------------
__global__ __launch_bounds__(256) void token_kernel(
    const float* __restrict__ pf,
    const float* __restrict__ tW1, const float* __restrict__ tb1,
    const float* __restrict__ tg1, const float* __restrict__ tbe1,
    const float* __restrict__ tW2, const float* __restrict__ tb2,
    const float* __restrict__ tg2, const float* __restrict__ tbe2,
    const int* __restrict__ center_idx, const float* __restrict__ pc,
    const float* __restrict__ sf0, const float* __restrict__ sf1,
    const float* __restrict__ sf2, float* __restrict__ out) {
    int bc = blockIdx.x;
    int b = bc >> 9;
    int t = threadIdx.x;
    __shared__ __align__(16) float tin[D_TOK];
    __shared__ float hh[TOK];
    __shared__ float red[8];
    int cidx = center_idx[bc];
    if (t < STEM) tin[t] = pf[((size_t)b * NPTS + cidx) * STEM + t];
    tin[128 + t] = sf0[(size_t)bc * TOK + t];
    tin[384 + t] = sf1[(size_t)bc * TOK + t];
    tin[640 + t] = sf2[(size_t)bc * TOK + t];
    if (t < 96) {
        int axis = t >> 5;
        int rem = t & 31;
        float c = pc[(size_t)bc * 3 + axis];
        int fi = (rem < 16) ? rem : rem - 16;
        float fr = expf(__fdiv_rn(-logf(10000.0f) * (float)fi, 15.0f));
        float ang = c * fr;
        tin[896 + t] = (rem < 16) ? sinf(ang) : cosf(ang);
    }
    __syncthreads();
    float acc = tb1[t];
    for (int i = 0; i < D_TOK; i += 4) {
        float4 x = *reinterpret_cast<const float4*>(&tin[i]);
        acc = fmaf(x.x, tW1[(i + 0) * TOK + t], acc);
        acc = fmaf(x.y, tW1[(i + 1) * TOK + t], acc);
        acc = fmaf(x.z, tW1[(i + 2) * TOK + t], acc);
        acc = fmaf(x.w, tW1[(i + 3) * TOK + t], acc);
    }
    int w = t >> 6, lane = t & 63;
    float s = acc, ss = acc * acc;
#pragma unroll
    for (int off = 32; off >= 1; off >>= 1) {
        s += __shfl_xor(s, off, 64);
        ss += __shfl_xor(ss, off, 64);
    }
    if (lane == 0) { red[w * 2] = s; red[w * 2 + 1] = ss; }
    __syncthreads();
    float S4 = red[0] + red[2] + red[4] + red[6];
    float SS4 = red[1] + red[3] + red[5] + red[7];
    float m = S4 * (1.0f / 256.0f);
    float var = SS4 * (1.0f / 256.0f) - m * m;
    float rs = rsqrtf(var + 1e-5f);
    float v = (acc - m) * rs * tg1[t] + tbe1[t];
    v = 0.5f * v * (1.0f + erff(v * 0.70710678118654752f));
    hh[t] = v;
    __syncthreads();
    float acc2 = tb2[t];
    for (int i = 0; i < TOK; i += 4) {
        float4 x = *reinterpret_cast<const float4*>(&hh[i]);
        acc2 = fmaf(x.x, tW2[(i + 0) * TOK + t], acc2);
        acc2 = fmaf(x.y, tW2[(i + 1) * TOK + t], acc2);
        acc2 = fmaf(x.z, tW2[(i + 2) * TOK + t], acc2);
        acc2 = fmaf(x.w, tW2[(i + 3) * TOK + t], acc2);
    }
    float s2 = acc2, ss2 = acc2 * acc2;
#pragma unroll
    for (int off = 32; off >= 1; off >>= 1) {
        s2 += __shfl_xor(s2, off, 64);
        ss2 += __shfl_xor(ss2, off, 64);
    }
    __syncthreads();
    if (lane == 0) { red[w * 2] = s2; red[w * 2 + 1] = ss2; }
    __syncthreads();
    float S42 = red[0] + red[2] + red[4] + red[6];
    float SS42 = red[1] + red[3] + red[5] + red[7];
    float m2 = S42 * (1.0f / 256.0f);
    float var2 = SS42 * (1.0f / 256.0f) - m2 * m2;
    float rs2 = rsqrtf(var2 + 1e-5f);
    float v2 = (acc2 - m2) * rs2 * tg2[t] + tbe2[t];
    out[(size_t)bc * TOK + t] = v2;
}

extern "C" void kernel_launch(void* const* d_in, const int* in_sizes, int n_in,
                              void* d_out, int out_size, void* d_ws, size_t ws_size,
                              hipStream_t stream) {
    const float* xyz  = (const float*)d_in[0];
    const float* pf   = (const float*)d_in[1];
    const float* sW1  = (const float*)d_in[2];
    const float* sb1  = (const float*)d_in[3];
    const float* sg1  = (const float*)d_in[4];
    const float* sbe1 = (const float*)d_in[5];
    const float* sW2  = (const float*)d_in[6];
    const float* sb2  = (const float*)d_in[7];
    const float* sg2  = (const float*)d_in[8];
    const float* sbe2 = (const float*)d_in[9];
    const float* tW1  = (const float*)d_in[10];
    const float* tb1  = (const float*)d_in[11];
    const float* tg1  = (const float*)d_in[12];
    const float* tbe1 = (const float*)d_in[13];
    const float* tW2  = (const float*)d_in[14];
    const float* tb2  = (const float*)d_in[15];
    const float* tg2  = (const float*)d_in[16];
    const float* tbe2 = (const float*)d_in[17];

    float* out_tok = (float*)d_out;
    float* out_pc  = out_tok + (size_t)BATCH * NCTR * TOK;

    char* ws = (char*)d_ws;
    int* center_idx = (int*)ws;   ws += (size_t)BATCH * NCTR * 4;
    float* pc_ws    = (float*)ws; ws += (size_t)BATCH * NCTR * 3 * 4;
    int* nbr0       = (int*)ws;   ws += (size_t)BATCH * NCTR * 16 * 4;
    int* nbr1       = (int*)ws;   ws += (size_t)BATCH * NCTR * 32 * 4;
    int* nbr2       = (int*)ws;   ws += (size_t)BATCH * NCTR * 64 * 4;
    float* sf0      = (float*)ws; ws += (size_t)BATCH * NCTR * TOK * 4;
    float* sf1      = (float*)ws; ws += (size_t)BATCH * NCTR * TOK * 4;
    float* sf2      = (float*)ws; ws += (size_t)BATCH * NCTR * TOK * 4;
    const size_t PK1_S = 16 * 5 * 64 * 16;   // ushorts per scale (W1)
    const size_t PK2_S = 16 * 8 * 64 * 16;   // ushorts per scale (W2)
    unsigned short* pkW1 = (unsigned short*)ws; ws += 3 * PK1_S * 2;
    unsigned short* pkW2 = (unsigned short*)ws; ws += 3 * PK2_S * 2;

    // pack weights (hi/lo bf16, fragment-ordered)
    {
        dim3 gp1((16 * 5 * 64 + 255) / 256, 3);
        pack_w<<<gp1, 256, 0, stream>>>(sW1, pkW1, D_IN, 5);
        dim3 gp2((16 * 8 * 64 + 255) / 256, 3);
        pack_w<<<gp2, 256, 0, stream>>>(sW2, pkW2, TOK, 8);
    }

    fps_kernel<<<BATCH, 256, 0, stream>>>(xyz, center_idx, pc_ws, out_pc);

    ballq_kernel<16><<<BATCH * NCTR / 4, 256, 0, stream>>>(xyz, pc_ws, nbr0, (float)(0.1 * 0.1));
    ballq_kernel<32><<<BATCH * NCTR / 4, 256, 0, stream>>>(xyz, pc_ws, nbr1, (float)(0.2 * 0.2));
    ballq_kernel<64><<<BATCH * NCTR / 4, 256, 0, stream>>>(xyz, pc_ws, nbr2, (float)(0.4 * 0.4));

    // rows = 8192*K, 128 rows per block
    scale_mfma<16><<<(BATCH * NCTR * 16) / 128, 256, 0, stream>>>(
        xyz, pf, pkW1 + 0 * PK1_S, sb1 + 0 * TOK, sg1 + 0 * TOK, sbe1 + 0 * TOK,
        pkW2 + 0 * PK2_S, sb2 + 0 * TOK, sg2 + 0 * TOK, sbe2 + 0 * TOK,
        nbr0, pc_ws, sf0);
    scale_mfma<32><<<(BATCH * NCTR * 32) / 128, 256, 0, stream>>>(
        xyz, pf, pkW1 + 1 * PK1_S, sb1 + 1 * TOK, sg1 + 1 * TOK, sbe1 + 1 * TOK,
        pkW2 + 1 * PK2_S, sb2 + 1 * TOK, sg2 + 1 * TOK, sbe2 + 1 * TOK,
        nbr1, pc_ws, sf1);
    scale_mfma<64><<<(BATCH * NCTR * 64) / 128, 256, 0, stream>>>(
        xyz, pf, pkW1 + 2 * PK1_S, sb1 + 2 * TOK, sg1 + 2 * TOK, sbe1 + 2 * TOK,
        pkW2 + 2 * PK2_S, sb2 + 2 * TOK, sg2 + 2 * TOK, sbe2 + 2 * TOK,
        nbr2, pc_ws, sf2);

    token_kernel<<<BATCH * NCTR, 256, 0, stream>>>(
        pf, tW1, tb1, tg1, tbe1, tW2, tb2, tg2, tbe2,
        center_idx, pc_ws, sf0, sf1, sf2, out_tok);
}

// Round 3
// 2639.396 us; speedup vs baseline: 3.0964x; 1.2384x over previous
//
#include <hip/hip_runtime.h>
#include <math.h>

#define BATCH 16
#define NPTS  4096
#define NCTR  512
#define STEM  128
#define TOK   256
#define D_IN  155   // 128 + 3 + 24
#define D_TOK 992   // 128 + 3*256 + 96

typedef short s16x8 __attribute__((ext_vector_type(8)));
typedef float f32x4 __attribute__((ext_vector_type(4)));

__device__ __forceinline__ unsigned short f2bf(float f) {
    unsigned u = __float_as_uint(f);
    u += 0x7FFF + ((u >> 16) & 1);   // round-to-nearest-even
    return (unsigned short)(u >> 16);
}
__device__ __forceinline__ float bf2f(unsigned short b) {
    return __uint_as_float(((unsigned)b) << 16);
}

// async global->LDS, 16B per lane; dst is wave-uniform base + lane*16
__device__ __forceinline__ void gload_lds16(const void* g, void* s) {
    __builtin_amdgcn_global_load_lds(
        (const __attribute__((address_space(1))) unsigned int*)g,
        (__attribute__((address_space(3))) unsigned int*)s, 16, 0, 0);
}

// exact, non-contracted squared distance to match numpy f32 rounding
__device__ __forceinline__ float sq3(float ax, float ay, float az,
                                     float bx, float by, float bz) {
    float dx = __fsub_rn(ax, bx);
    float dy = __fsub_rn(ay, by);
    float dz = __fsub_rn(az, bz);
    float d = __fmul_rn(dx, dx);
    d = __fadd_rn(d, __fmul_rn(dy, dy));
    d = __fadd_rn(d, __fmul_rn(dz, dz));
    return d;
}

// ---------------- FPS: one block per batch (unchanged, index-exact) -------
__global__ __launch_bounds__(256) void fps_kernel(const float* __restrict__ xyz,
                                                  int* __restrict__ center_idx,
                                                  float* __restrict__ pc_ws,
                                                  float* __restrict__ pc_out) {
    int b = blockIdx.x;
    int t = threadIdx.x;
    const float* X = xyz + (size_t)b * NPTS * 3;
    float px[16], py[16], pz[16], dist[16];
#pragma unroll
    for (int j = 0; j < 16; ++j) {
        int i = t + 256 * j;
        px[j] = X[i * 3 + 0];
        py[j] = X[i * 3 + 1];
        pz[j] = X[i * 3 + 2];
        dist[j] = 1e10f;
    }
    __shared__ float sc[3];
    __shared__ int sfar;
    __shared__ float swv[4];
    __shared__ int swi[4];
    int far = 0;
    for (int s = 0; s < NCTR; ++s) {
        if (t == 0) {
            float cx = X[far * 3], cy = X[far * 3 + 1], cz = X[far * 3 + 2];
            sc[0] = cx; sc[1] = cy; sc[2] = cz;
            center_idx[b * NCTR + s] = far;
            size_t po = (size_t)(b * NCTR + s) * 3;
            pc_ws[po] = cx; pc_ws[po + 1] = cy; pc_ws[po + 2] = cz;
            pc_out[po] = cx; pc_out[po + 1] = cy; pc_out[po + 2] = cz;
        }
        __syncthreads();
        float cx = sc[0], cy = sc[1], cz = sc[2];
        float bv = -1.0f;
        int bi = 0;
#pragma unroll
        for (int j = 0; j < 16; ++j) {
            float d = sq3(px[j], py[j], pz[j], cx, cy, cz);
            float nd = fminf(dist[j], d);
            dist[j] = nd;
            if (nd > bv) { bv = nd; bi = t + 256 * j; }
        }
#pragma unroll
        for (int off = 32; off >= 1; off >>= 1) {
            float ov = __shfl_xor(bv, off, 64);
            int   oi = __shfl_xor(bi, off, 64);
            if (ov > bv || (ov == bv && oi < bi)) { bv = ov; bi = oi; }
        }
        if ((t & 63) == 0) { swv[t >> 6] = bv; swi[t >> 6] = bi; }
        __syncthreads();
        if (t == 0) {
            for (int w2 = 1; w2 < 4; ++w2) {
                float ov = swv[w2]; int oi = swi[w2];
                if (ov > bv || (ov == bv && oi < bi)) { bv = ov; bi = oi; }
            }
            sfar = bi;
        }
        __syncthreads();
        far = sfar;
    }
}

// ---------------- Ball query (unchanged) ----------------------------------
template <int K>
__global__ __launch_bounds__(256) void ballq_kernel(const float* __restrict__ xyz,
                                                    const float* __restrict__ pc,
                                                    int* __restrict__ nbr,
                                                    float rr) {
    int cid = blockIdx.x * 4 + (threadIdx.x >> 6);
    int lane = threadIdx.x & 63;
    int b = cid >> 9;
    const float* X = xyz + (size_t)b * NPTS * 3;
    float cx = pc[(size_t)cid * 3 + 0];
    float cy = pc[(size_t)cid * 3 + 1];
    float cz = pc[(size_t)cid * 3 + 2];
    int cnt = 0, first = 0;
    bool have_first = false;
    long long base = (long long)cid * K;
    for (int it = 0; it < NPTS / 64; ++it) {
        int i = it * 64 + lane;
        float d = sq3(cx, cy, cz, X[i * 3], X[i * 3 + 1], X[i * 3 + 2]);
        bool ok = d <= rr;
        unsigned long long mask = __ballot(ok);
        if (!have_first && mask) {
            first = it * 64 + (int)__builtin_ctzll(mask);
            have_first = true;
        }
        int pos = cnt + (int)__popcll(mask & ((1ull << lane) - 1ull));
        if (ok && pos < K) nbr[base + pos] = i;
        cnt += (int)__popcll(mask);
        if (cnt >= K) break;
    }
    int fill = cnt < K ? cnt : K;
    for (int j = fill + lane; j < K; j += 64) nbr[base + j] = first;
}

// ---------------- Weight pack: f32 row-major -> hi/lo bf16 MFMA B-frags ----
__global__ __launch_bounds__(256) void pack_w(const float* __restrict__ Wbase,
                                              unsigned short* __restrict__ out,
                                              int Kdim, int KS) {
    int s = blockIdx.y;
    const float* W = Wbase + (size_t)s * Kdim * TOK;
    unsigned short* o = out + (size_t)s * 16 * KS * 64 * 16;
    int tid = blockIdx.x * 256 + threadIdx.x;
    if (tid >= 16 * KS * 64) return;
    int lane = tid & 63;
    int frag = tid >> 6;
    int ks = frag % KS;
    int ct = frag / KS;
    int col = ct * 16 + (lane & 15);
    int k0 = ks * 32 + (lane >> 4) * 8;
    unsigned short* dst = o + (size_t)tid * 16;
#pragma unroll
    for (int j = 0; j < 8; ++j) {
        int k = k0 + j;
        float v = (k < Kdim) ? W[(size_t)k * TOK + col] : 0.0f;
        unsigned short h = f2bf(v);
        dst[j] = h;
        dst[8 + j] = f2bf(v - bf2f(h));
    }
}

// ---------------- Per-scale grouped MLP via bf16x3 MFMA --------------------
// Block = 4 waves x 32 rows. B-frags staged in LDS (once per block, not per
// wave). MLP2 split per 16-row half (rb) to bound register liveness; all
// accumulator indexing compile-time (rule #20: no scratch).
template <int K>
__global__ __launch_bounds__(256, 2) void scale_mfma(
    const float* __restrict__ xyz, const float* __restrict__ pf,
    const unsigned short* __restrict__ pk1, const float* __restrict__ b1,
    const float* __restrict__ g1, const float* __restrict__ be1,
    const unsigned short* __restrict__ pk2, const float* __restrict__ b2,
    const float* __restrict__ g2, const float* __restrict__ be2,
    const int* __restrict__ nbr, const float* __restrict__ pc,
    float* __restrict__ outf) {
    __shared__ __align__(16) unsigned short bstage[16 * 64 * 16];  // 32 KB
    __shared__ __align__(16) float hbuf[4][16][68];                // 17 KB
    __shared__ float maxbuf[4][256];                               // 4 KB
    const int w = threadIdx.x >> 6, l = threadIdx.x & 63;
    const int lg = l >> 4, li = l & 15;
    const int rowbase = blockIdx.x * 128 + w * 32;

    int nb[2];
    float rel[2][3];
#pragma unroll
    for (int rb = 0; rb < 2; ++rb) {
        int row = rowbase + rb * 16 + li;
        int c = row / K;
        int b = c >> 9;
        int n = nbr[row];
        nb[rb] = (b << 12) + n;
        const float* X = xyz + ((size_t)nb[rb]) * 3;
        const float* C = pc + (size_t)c * 3;
        rel[rb][0] = __fsub_rn(X[0], C[0]);
        rel[rb][1] = __fsub_rn(X[1], C[1]);
        rel[rb][2] = __fsub_rn(X[2], C[2]);
    }

    // ---------------- MLP1: [32 x 160] @ [160 x 256] (bf16x3) -------------
    f32x4 acc[2][16];
#pragma unroll
    for (int rb = 0; rb < 2; ++rb)
#pragma unroll
        for (int t = 0; t < 16; ++t) acc[rb][t] = (f32x4){0.f, 0.f, 0.f, 0.f};

#pragma unroll
    for (int ks = 0; ks < 5; ++ks) {
        __syncthreads();  // previous bstage fully consumed
        // stage B1[ks]: wave w loads ct = 4w..4w+3 (2 KB each, 2x16B/lane)
#pragma unroll
        for (int ctl = 0; ctl < 4; ++ctl) {
            const unsigned short* s0 = pk1 + ((size_t)((w * 4 + ctl) * 5 + ks) * 64) * 16;
            unsigned short* d0 = bstage + (size_t)(w * 4 + ctl) * 64 * 16;
            gload_lds16(s0 + (size_t)l * 8, d0);
            gload_lds16(s0 + 512 + (size_t)l * 8, d0 + 512);
        }
        // build A frags while loads are in flight
        s16x8 Ah[2], Al[2];
#pragma unroll
        for (int rb = 0; rb < 2; ++rb) {
            float v[8];
            if (ks < 4) {
                const float* src = pf + (size_t)nb[rb] * STEM + ks * 32 + lg * 8;
                float4 f0 = *(const float4*)src;
                float4 f1 = *(const float4*)(src + 4);
                v[0] = f0.x; v[1] = f0.y; v[2] = f0.z; v[3] = f0.w;
                v[4] = f1.x; v[5] = f1.y; v[6] = f1.z; v[7] = f1.w;
            } else {
#pragma unroll
                for (int j = 0; j < 8; ++j) {
                    int ch = lg * 8 + j;  // feature 128+ch
                    float val = 0.0f;
                    if (ch < 3) {
                        val = rel[rb][ch];
                    } else if (ch < 27) {
                        int rem = ch - 3;
                        int axis = rem >> 3, r8 = rem & 7;
                        int fi = (r8 < 4) ? r8 : r8 - 4;
                        float fr = expf(__fdiv_rn(-logf(10000.0f) * (float)fi, 3.0f));
                        float ang = rel[rb][axis] * fr;
                        val = (r8 < 4) ? sinf(ang) : cosf(ang);
                    }
                    v[j] = val;
                }
            }
#pragma unroll
            for (int j = 0; j < 8; ++j) {
                unsigned short h = f2bf(v[j]);
                Ah[rb][j] = (short)h;
                Al[rb][j] = (short)f2bf(v[j] - bf2f(h));
            }
        }
        __syncthreads();  // staging complete
#pragma unroll
        for (int ct = 0; ct < 16; ++ct) {
            const s16x8* bp = (const s16x8*)(bstage + ((size_t)ct * 64 + l) * 16);
            s16x8 Bh = bp[0], Bl = bp[1];
#pragma unroll
            for (int rb = 0; rb < 2; ++rb) {
                acc[rb][ct] = __builtin_amdgcn_mfma_f32_16x16x32_bf16(Ah[rb], Bh, acc[rb][ct], 0, 0, 0);
                acc[rb][ct] = __builtin_amdgcn_mfma_f32_16x16x32_bf16(Ah[rb], Bl, acc[rb][ct], 0, 0, 0);
                acc[rb][ct] = __builtin_amdgcn_mfma_f32_16x16x32_bf16(Al[rb], Bh, acc[rb][ct], 0, 0, 0);
            }
        }
    }

    // ---------------- bias + LN1 + GELU (params scoped; stats via shfl) ---
    {
        float b1v[16], g1v[16], be1v[16];
#pragma unroll
        for (int t = 0; t < 16; ++t) {
            int col = t * 16 + li;
            b1v[t] = b1[col]; g1v[t] = g1[col]; be1v[t] = be1[col];
        }
#pragma unroll
        for (int rb = 0; rb < 2; ++rb) {
#pragma unroll
            for (int reg = 0; reg < 4; ++reg) {
                float s = 0.f, ss = 0.f;
#pragma unroll
                for (int t = 0; t < 16; ++t) {
                    float x = acc[rb][t][reg] + b1v[t];
                    s += x; ss = fmaf(x, x, ss);
                }
#pragma unroll
                for (int m = 1; m <= 8; m <<= 1) {
                    s += __shfl_xor(s, m, 64);
                    ss += __shfl_xor(ss, m, 64);
                }
                float mean = s * (1.0f / 256.0f);
                float var = ss * (1.0f / 256.0f) - mean * mean;
                float rs = rsqrtf(var + 1e-5f);
#pragma unroll
                for (int t = 0; t < 16; ++t) {
                    float x = acc[rb][t][reg] + b1v[t];
                    float vv = (x - mean) * rs * g1v[t] + be1v[t];
                    acc[rb][t][reg] = 0.5f * vv * (1.0f + erff(vv * 0.70710678118654752f));
                }
            }
        }
    }

    // ---------------- MLP2: per-rb [16 x 256] @ [256 x 256] (bf16x3) ------
    float mrb[2][16];
#pragma unroll
    for (int rb = 0; rb < 2; ++rb) {
        f32x4 acc2[16];
#pragma unroll
        for (int t = 0; t < 16; ++t) acc2[t] = (f32x4){0.f, 0.f, 0.f, 0.f};

#pragma unroll
        for (int c = 0; c < 4; ++c) {
            // transpose 16x64 chunk of h into wave-private LDS; frees acc[rb][4c..]
#pragma unroll
            for (int tl = 0; tl < 4; ++tl)
#pragma unroll
                for (int reg = 0; reg < 4; ++reg)
                    hbuf[w][lg * 4 + reg][tl * 16 + li] = acc[rb][4 * c + tl][reg];
#pragma unroll
            for (int kl = 0; kl < 2; ++kl) {
                const int ksg = 2 * c + kl;
                __syncthreads();  // previous bstage fully consumed
#pragma unroll
                for (int ctl = 0; ctl < 4; ++ctl) {
                    const unsigned short* s0 = pk2 + ((size_t)((w * 4 + ctl) * 8 + ksg) * 64) * 16;
                    unsigned short* d0 = bstage + (size_t)(w * 4 + ctl) * 64 * 16;
                    gload_lds16(s0 + (size_t)l * 8, d0);
                    gload_lds16(s0 + 512 + (size_t)l * 8, d0 + 512);
                }
                // A frag from transposed h (wave-private, no barrier needed)
                const float* hp = &hbuf[w][li][kl * 32 + lg * 8];
                float4 f0 = *(const float4*)hp;
                float4 f1 = *(const float4*)(hp + 4);
                float v[8] = {f0.x, f0.y, f0.z, f0.w, f1.x, f1.y, f1.z, f1.w};
                s16x8 Ah2, Al2;
#pragma unroll
                for (int j = 0; j < 8; ++j) {
                    unsigned short h = f2bf(v[j]);
                    Ah2[j] = (short)h;
                    Al2[j] = (short)f2bf(v[j] - bf2f(h));
                }
                __syncthreads();  // staging complete
#pragma unroll
                for (int ct = 0; ct < 16; ++ct) {
                    const s16x8* bp = (const s16x8*)(bstage + ((size_t)ct * 64 + l) * 16);
                    s16x8 Bh = bp[0], Bl = bp[1];
                    acc2[ct] = __builtin_amdgcn_mfma_f32_16x16x32_bf16(Ah2, Bh, acc2[ct], 0, 0, 0);
                    acc2[ct] = __builtin_amdgcn_mfma_f32_16x16x32_bf16(Ah2, Bl, acc2[ct], 0, 0, 0);
                    acc2[ct] = __builtin_amdgcn_mfma_f32_16x16x32_bf16(Al2, Bh, acc2[ct], 0, 0, 0);
                }
            }
        }

        // ---- bias + LN2 + row-max for this 16-row half --------------------
        {
            float b2v[16], g2v[16], be2v[16];
#pragma unroll
            for (int t = 0; t < 16; ++t) {
                int col = t * 16 + li;
                b2v[t] = b2[col]; g2v[t] = g2[col]; be2v[t] = be2[col];
            }
#pragma unroll
            for (int reg = 0; reg < 4; ++reg) {
                float s = 0.f, ss = 0.f;
#pragma unroll
                for (int t = 0; t < 16; ++t) {
                    float x = acc2[t][reg] + b2v[t];
                    s += x; ss = fmaf(x, x, ss);
                }
#pragma unroll
                for (int m = 1; m <= 8; m <<= 1) {
                    s += __shfl_xor(s, m, 64);
                    ss += __shfl_xor(ss, m, 64);
                }
                float mean = s * (1.0f / 256.0f);
                float var = ss * (1.0f / 256.0f) - mean * mean;
                float rs = rsqrtf(var + 1e-5f);
#pragma unroll
                for (int t = 0; t < 16; ++t) {
                    float x = acc2[t][reg] + b2v[t];
                    acc2[t][reg] = (x - mean) * rs * g2v[t] + be2v[t];
                }
            }
        }
#pragma unroll
        for (int t = 0; t < 16; ++t) {
            float m = fmaxf(fmaxf(acc2[t][0], acc2[t][1]),
                            fmaxf(acc2[t][2], acc2[t][3]));
            m = fmaxf(m, __shfl_xor(m, 16, 64));
            m = fmaxf(m, __shfl_xor(m, 32, 64));
            mrb[rb][t] = m;
        }
    }

    // ---------------- emit per-center max ---------------------------------
    if (K == 16) {
        if (lg == 0) {
#pragma unroll
            for (int rb = 0; rb < 2; ++rb) {
                int c = (rowbase + rb * 16) >> 4;
#pragma unroll
                for (int t = 0; t < 16; ++t)
                    outf[(size_t)c * TOK + t * 16 + li] = mrb[rb][t];
            }
        }
    } else if (K == 32) {
        if (lg == 0) {
            int c = rowbase >> 5;
#pragma unroll
            for (int t = 0; t < 16; ++t)
                outf[(size_t)c * TOK + t * 16 + li] = fmaxf(mrb[0][t], mrb[1][t]);
        }
    } else {  // K == 64: combine the two waves of each center via LDS
        if (lg == 0) {
#pragma unroll
            for (int t = 0; t < 16; ++t)
                maxbuf[w][t * 16 + li] = fmaxf(mrb[0][t], mrb[1][t]);
        }
        __syncthreads();
        if ((w & 1) == 0 && lg == 0) {
            int c = rowbase >> 6;
#pragma unroll
            for (int t = 0; t < 16; ++t) {
                int cc = t * 16 + li;
                outf[(size_t)c * TOK + cc] = fmaxf(maxbuf[w][cc], maxbuf[w + 1][cc]);
            }
        }
    }
}

// ---------------- Token MLP (unchanged, f32) -------------------------------
__global__ __launch_bounds__(256) void token_kernel(
    const float* __restrict__ pf,
    const float* __restrict__ tW1, const float* __restrict__ tb1,
    const float* __restrict__ tg1, const float* __restrict__ tbe1,
    const float* __restrict__ tW2, const float* __restrict__ tb2,
    const float* __restrict__ tg2, const float* __restrict__ tbe2,
    const int* __restrict__ center_idx, const float* __restrict__ pc,
    const float* __restrict__ sf0, const float* __restrict__ sf1,
    const float* __restrict__ sf2, float* __restrict__ out) {
    int bc = blockIdx.x;
    int b = bc >> 9;
    int t = threadIdx.x;
    __shared__ __align__(16) float tin[D_TOK];
    __shared__ float hh[TOK];
    __shared__ float red[8];
    int cidx = center_idx[bc];
    if (t < STEM) tin[t] = pf[((size_t)b * NPTS + cidx) * STEM + t];
    tin[128 + t] = sf0[(size_t)bc * TOK + t];
    tin[384 + t] = sf1[(size_t)bc * TOK + t];
    tin[640 + t] = sf2[(size_t)bc * TOK + t];
    if (t < 96) {
        int axis = t >> 5;
        int rem = t & 31;
        float c = pc[(size_t)bc * 3 + axis];
        int fi = (rem < 16) ? rem : rem - 16;
        float fr = expf(__fdiv_rn(-logf(10000.0f) * (float)fi, 15.0f));
        float ang = c * fr;
        tin[896 + t] = (rem < 16) ? sinf(ang) : cosf(ang);
    }
    __syncthreads();
    float acc = tb1[t];
    for (int i = 0; i < D_TOK; i += 4) {
        float4 x = *reinterpret_cast<const float4*>(&tin[i]);
        acc = fmaf(x.x, tW1[(i + 0) * TOK + t], acc);
        acc = fmaf(x.y, tW1[(i + 1) * TOK + t], acc);
        acc = fmaf(x.z, tW1[(i + 2) * TOK + t], acc);
        acc = fmaf(x.w, tW1[(i + 3) * TOK + t], acc);
    }
    int w = t >> 6, lane = t & 63;
    float s = acc, ss = acc * acc;
#pragma unroll
    for (int off = 32; off >= 1; off >>= 1) {
        s += __shfl_xor(s, off, 64);
        ss += __shfl_xor(ss, off, 64);
    }
    if (lane == 0) { red[w * 2] = s; red[w * 2 + 1] = ss; }
    __syncthreads();
    float S4 = red[0] + red[2] + red[4] + red[6];
    float SS4 = red[1] + red[3] + red[5] + red[7];
    float m = S4 * (1.0f / 256.0f);
    float var = SS4 * (1.0f / 256.0f) - m * m;
    float rs = rsqrtf(var + 1e-5f);
    float v = (acc - m) * rs * tg1[t] + tbe1[t];
    v = 0.5f * v * (1.0f + erff(v * 0.70710678118654752f));
    hh[t] = v;
    __syncthreads();
    float acc2 = tb2[t];
    for (int i = 0; i < TOK; i += 4) {
        float4 x = *reinterpret_cast<const float4*>(&hh[i]);
        acc2 = fmaf(x.x, tW2[(i + 0) * TOK + t], acc2);
        acc2 = fmaf(x.y, tW2[(i + 1) * TOK + t], acc2);
        acc2 = fmaf(x.z, tW2[(i + 2) * TOK + t], acc2);
        acc2 = fmaf(x.w, tW2[(i + 3) * TOK + t], acc2);
    }
    float s2 = acc2, ss2 = acc2 * acc2;
#pragma unroll
    for (int off = 32; off >= 1; off >>= 1) {
        s2 += __shfl_xor(s2, off, 64);
        ss2 += __shfl_xor(ss2, off, 64);
    }
    __syncthreads();
    if (lane == 0) { red[w * 2] = s2; red[w * 2 + 1] = ss2; }
    __syncthreads();
    float S42 = red[0] + red[2] + red[4] + red[6];
    float SS42 = red[1] + red[3] + red[5] + red[7];
    float m2 = S42 * (1.0f / 256.0f);
    float var2 = SS42 * (1.0f / 256.0f) - m2 * m2;
    float rs2 = rsqrtf(var2 + 1e-5f);
    float v2 = (acc2 - m2) * rs2 * tg2[t] + tbe2[t];
    out[(size_t)bc * TOK + t] = v2;
}

extern "C" void kernel_launch(void* const* d_in, const int* in_sizes, int n_in,
                              void* d_out, int out_size, void* d_ws, size_t ws_size,
                              hipStream_t stream) {
    const float* xyz  = (const float*)d_in[0];
    const float* pf   = (const float*)d_in[1];
    const float* sW1  = (const float*)d_in[2];
    const float* sb1  = (const float*)d_in[3];
    const float* sg1  = (const float*)d_in[4];
    const float* sbe1 = (const float*)d_in[5];
    const float* sW2  = (const float*)d_in[6];
    const float* sb2  = (const float*)d_in[7];
    const float* sg2  = (const float*)d_in[8];
    const float* sbe2 = (const float*)d_in[9];
    const float* tW1  = (const float*)d_in[10];
    const float* tb1  = (const float*)d_in[11];
    const float* tg1  = (const float*)d_in[12];
    const float* tbe1 = (const float*)d_in[13];
    const float* tW2  = (const float*)d_in[14];
    const float* tb2  = (const float*)d_in[15];
    const float* tg2  = (const float*)d_in[16];
    const float* tbe2 = (const float*)d_in[17];

    float* out_tok = (float*)d_out;
    float* out_pc  = out_tok + (size_t)BATCH * NCTR * TOK;

    char* ws = (char*)d_ws;
    int* center_idx = (int*)ws;   ws += (size_t)BATCH * NCTR * 4;
    float* pc_ws    = (float*)ws; ws += (size_t)BATCH * NCTR * 3 * 4;
    int* nbr0       = (int*)ws;   ws += (size_t)BATCH * NCTR * 16 * 4;
    int* nbr1       = (int*)ws;   ws += (size_t)BATCH * NCTR * 32 * 4;
    int* nbr2       = (int*)ws;   ws += (size_t)BATCH * NCTR * 64 * 4;
    float* sf0      = (float*)ws; ws += (size_t)BATCH * NCTR * TOK * 4;
    float* sf1      = (float*)ws; ws += (size_t)BATCH * NCTR * TOK * 4;
    float* sf2      = (float*)ws; ws += (size_t)BATCH * NCTR * TOK * 4;
    const size_t PK1_S = 16 * 5 * 64 * 16;   // ushorts per scale (W1)
    const size_t PK2_S = 16 * 8 * 64 * 16;   // ushorts per scale (W2)
    unsigned short* pkW1 = (unsigned short*)ws; ws += 3 * PK1_S * 2;
    unsigned short* pkW2 = (unsigned short*)ws; ws += 3 * PK2_S * 2;

    {
        dim3 gp1((16 * 5 * 64 + 255) / 256, 3);
        pack_w<<<gp1, 256, 0, stream>>>(sW1, pkW1, D_IN, 5);
        dim3 gp2((16 * 8 * 64 + 255) / 256, 3);
        pack_w<<<gp2, 256, 0, stream>>>(sW2, pkW2, TOK, 8);
    }

    fps_kernel<<<BATCH, 256, 0, stream>>>(xyz, center_idx, pc_ws, out_pc);

    ballq_kernel<16><<<BATCH * NCTR / 4, 256, 0, stream>>>(xyz, pc_ws, nbr0, (float)(0.1 * 0.1));
    ballq_kernel<32><<<BATCH * NCTR / 4, 256, 0, stream>>>(xyz, pc_ws, nbr1, (float)(0.2 * 0.2));
    ballq_kernel<64><<<BATCH * NCTR / 4, 256, 0, stream>>>(xyz, pc_ws, nbr2, (float)(0.4 * 0.4));

    scale_mfma<16><<<(BATCH * NCTR * 16) / 128, 256, 0, stream>>>(
        xyz, pf, pkW1 + 0 * PK1_S, sb1 + 0 * TOK, sg1 + 0 * TOK, sbe1 + 0 * TOK,
        pkW2 + 0 * PK2_S, sb2 + 0 * TOK, sg2 + 0 * TOK, sbe2 + 0 * TOK,
        nbr0, pc_ws, sf0);
    scale_mfma<32><<<(BATCH * NCTR * 32) / 128, 256, 0, stream>>>(
        xyz, pf, pkW1 + 1 * PK1_S, sb1 + 1 * TOK, sg1 + 1 * TOK, sbe1 + 1 * TOK,
        pkW2 + 1 * PK2_S, sb2 + 1 * TOK, sg2 + 1 * TOK, sbe2 + 1 * TOK,
        nbr1, pc_ws, sf1);
    scale_mfma<64><<<(BATCH * NCTR * 64) / 128, 256, 0, stream>>>(
        xyz, pf, pkW1 + 2 * PK1_S, sb1 + 2 * TOK, sg1 + 2 * TOK, sbe1 + 2 * TOK,
        pkW2 + 2 * PK2_S, sb2 + 2 * TOK, sg2 + 2 * TOK, sbe2 + 2 * TOK,
        nbr2, pc_ws, sf2);

    token_kernel<<<BATCH * NCTR, 256, 0, stream>>>(
        pf, tW1, tb1, tg1, tbe1, tW2, tb2, tg2, tbe2,
        center_idx, pc_ws, sf0, sf1, sf2, out_tok);
}

// Round 4
// 2500.574 us; speedup vs baseline: 3.2683x; 1.0555x over previous
//
#include <hip/hip_runtime.h>
#include <math.h>

#define BATCH 16
#define NPTS  4096
#define NCTR  512
#define STEM  128
#define TOK   256
#define D_IN  155   // 128 + 3 + 24
#define D_TOK 992   // 128 + 3*256 + 96

typedef short s16x8 __attribute__((ext_vector_type(8)));
typedef float f32x4 __attribute__((ext_vector_type(4)));

__device__ __forceinline__ unsigned short f2bf(float f) {
    unsigned u = __float_as_uint(f);
    u += 0x7FFF + ((u >> 16) & 1);   // round-to-nearest-even
    return (unsigned short)(u >> 16);
}
__device__ __forceinline__ float bf2f(unsigned short b) {
    return __uint_as_float(((unsigned)b) << 16);
}

// async global->LDS, 16B per lane; dst is wave-uniform base + lane*16
__device__ __forceinline__ void gload_lds16(const void* g, void* s) {
    __builtin_amdgcn_global_load_lds(
        (const __attribute__((address_space(1))) unsigned int*)g,
        (__attribute__((address_space(3))) unsigned int*)s, 16, 0, 0);
}

// split 8 f32 -> hi/lo bf16 fragments via v_cvt_pk_bf16_f32 (RNE, matches f2bf)
__device__ __forceinline__ void bsplit8(const float* v, s16x8& hi, s16x8& lo) {
    union { s16x8 s; unsigned w[4]; } H, L;
#pragma unroll
    for (int p = 0; p < 4; ++p) {
        unsigned hp, lp;
        asm("v_cvt_pk_bf16_f32 %0, %1, %2" : "=v"(hp) : "v"(v[2 * p]), "v"(v[2 * p + 1]));
        float r0 = v[2 * p]     - __uint_as_float(hp << 16);
        float r1 = v[2 * p + 1] - __uint_as_float(hp & 0xffff0000u);
        asm("v_cvt_pk_bf16_f32 %0, %1, %2" : "=v"(lp) : "v"(r0), "v"(r1));
        H.w[p] = hp; L.w[p] = lp;
    }
    hi = H.s; lo = L.s;
}

// pack two f32 into two (hi16|lo16) u32 words
__device__ __forceinline__ void pkpair(float v0, float v1, unsigned& w0, unsigned& w1) {
    unsigned hp, lp;
    asm("v_cvt_pk_bf16_f32 %0, %1, %2" : "=v"(hp) : "v"(v0), "v"(v1));
    float r0 = v0 - __uint_as_float(hp << 16);
    float r1 = v1 - __uint_as_float(hp & 0xffff0000u);
    asm("v_cvt_pk_bf16_f32 %0, %1, %2" : "=v"(lp) : "v"(r0), "v"(r1));
    w0 = (hp << 16) | (lp & 0xffffu);
    w1 = (hp & 0xffff0000u) | (lp >> 16);
}

// exact, non-contracted squared distance to match numpy f32 rounding
__device__ __forceinline__ float sq3(float ax, float ay, float az,
                                     float bx, float by, float bz) {
    float dx = __fsub_rn(ax, bx);
    float dy = __fsub_rn(ay, by);
    float dz = __fsub_rn(az, bz);
    float d = __fmul_rn(dx, dx);
    d = __fadd_rn(d, __fmul_rn(dy, dy));
    d = __fadd_rn(d, __fmul_rn(dz, dz));
    return d;
}

// ---------------- FPS: one block per batch (unchanged, index-exact) -------
__global__ __launch_bounds__(256) void fps_kernel(const float* __restrict__ xyz,
                                                  int* __restrict__ center_idx,
                                                  float* __restrict__ pc_ws,
                                                  float* __restrict__ pc_out) {
    int b = blockIdx.x;
    int t = threadIdx.x;
    const float* X = xyz + (size_t)b * NPTS * 3;
    float px[16], py[16], pz[16], dist[16];
#pragma unroll
    for (int j = 0; j < 16; ++j) {
        int i = t + 256 * j;
        px[j] = X[i * 3 + 0];
        py[j] = X[i * 3 + 1];
        pz[j] = X[i * 3 + 2];
        dist[j] = 1e10f;
    }
    __shared__ float sc[3];
    __shared__ int sfar;
    __shared__ float swv[4];
    __shared__ int swi[4];
    int far = 0;
    for (int s = 0; s < NCTR; ++s) {
        if (t == 0) {
            float cx = X[far * 3], cy = X[far * 3 + 1], cz = X[far * 3 + 2];
            sc[0] = cx; sc[1] = cy; sc[2] = cz;
            center_idx[b * NCTR + s] = far;
            size_t po = (size_t)(b * NCTR + s) * 3;
            pc_ws[po] = cx; pc_ws[po + 1] = cy; pc_ws[po + 2] = cz;
            pc_out[po] = cx; pc_out[po + 1] = cy; pc_out[po + 2] = cz;
        }
        __syncthreads();
        float cx = sc[0], cy = sc[1], cz = sc[2];
        float bv = -1.0f;
        int bi = 0;
#pragma unroll
        for (int j = 0; j < 16; ++j) {
            float d = sq3(px[j], py[j], pz[j], cx, cy, cz);
            float nd = fminf(dist[j], d);
            dist[j] = nd;
            if (nd > bv) { bv = nd; bi = t + 256 * j; }
        }
#pragma unroll
        for (int off = 32; off >= 1; off >>= 1) {
            float ov = __shfl_xor(bv, off, 64);
            int   oi = __shfl_xor(bi, off, 64);
            if (ov > bv || (ov == bv && oi < bi)) { bv = ov; bi = oi; }
        }
        if ((t & 63) == 0) { swv[t >> 6] = bv; swi[t >> 6] = bi; }
        __syncthreads();
        if (t == 0) {
            for (int w2 = 1; w2 < 4; ++w2) {
                float ov = swv[w2]; int oi = swi[w2];
                if (ov > bv || (ov == bv && oi < bi)) { bv = ov; bi = oi; }
            }
            sfar = bi;
        }
        __syncthreads();
        far = sfar;
    }
}

// ---------------- Ball query (unchanged) ----------------------------------
template <int K>
__global__ __launch_bounds__(256) void ballq_kernel(const float* __restrict__ xyz,
                                                    const float* __restrict__ pc,
                                                    int* __restrict__ nbr,
                                                    float rr) {
    int cid = blockIdx.x * 4 + (threadIdx.x >> 6);
    int lane = threadIdx.x & 63;
    int b = cid >> 9;
    const float* X = xyz + (size_t)b * NPTS * 3;
    float cx = pc[(size_t)cid * 3 + 0];
    float cy = pc[(size_t)cid * 3 + 1];
    float cz = pc[(size_t)cid * 3 + 2];
    int cnt = 0, first = 0;
    bool have_first = false;
    long long base = (long long)cid * K;
    for (int it = 0; it < NPTS / 64; ++it) {
        int i = it * 64 + lane;
        float d = sq3(cx, cy, cz, X[i * 3], X[i * 3 + 1], X[i * 3 + 2]);
        bool ok = d <= rr;
        unsigned long long mask = __ballot(ok);
        if (!have_first && mask) {
            first = it * 64 + (int)__builtin_ctzll(mask);
            have_first = true;
        }
        int pos = cnt + (int)__popcll(mask & ((1ull << lane) - 1ull));
        if (ok && pos < K) nbr[base + pos] = i;
        cnt += (int)__popcll(mask);
        if (cnt >= K) break;
    }
    int fill = cnt < K ? cnt : K;
    for (int j = fill + lane; j < K; j += 64) nbr[base + j] = first;
}

// ---------------- Weight pack: hi-plane/lo-plane bf16 MFMA B-frags --------
// frag f = ct*KS + ks (2048 B): bytes [0,1024) = hi plane (lane l at l*16B),
// bytes [1024,2048) = lo plane. Read: Bh at l*8 ush, Bl at 512 + l*8.
__global__ __launch_bounds__(256) void pack_w(const float* __restrict__ Wbase,
                                              unsigned short* __restrict__ out,
                                              int Kdim, int KS) {
    int s = blockIdx.y;
    const float* W = Wbase + (size_t)s * Kdim * TOK;
    unsigned short* o = out + (size_t)s * 16 * KS * 64 * 16;
    int tid = blockIdx.x * 256 + threadIdx.x;
    if (tid >= 16 * KS * 64) return;
    int lane = tid & 63;
    int frag = tid >> 6;
    int ks = frag % KS;
    int ct = frag / KS;
    int col = ct * 16 + (lane & 15);
    int k0 = ks * 32 + (lane >> 4) * 8;
    unsigned short* hi = o + (size_t)frag * 1024 + lane * 8;
    unsigned short* lo = hi + 512;
#pragma unroll
    for (int j = 0; j < 8; ++j) {
        int k = k0 + j;
        float v = (k < Kdim) ? W[(size_t)k * TOK + col] : 0.0f;
        unsigned short h = f2bf(v);
        hi[j] = h;
        lo[j] = f2bf(v - bf2f(h));
    }
}

// ---------------- Per-scale grouped MLP via bf16x3 MFMA --------------------
// Block = 64 rows x 256 cols; wave w owns cols [64w, 64w+64) (ct 4w..4w+3).
// acc1/acc2 are 4x4 f32x4 (64 VGPR each); h parked in LDS as packed bf16
// hi|lo u32, in two 128-col halves. B staging is wave-private (no barriers).
template <int K>
__global__ __launch_bounds__(256, 2) void scale_mfma(
    const float* __restrict__ xyz, const float* __restrict__ pf,
    const unsigned short* __restrict__ pk1, const float* __restrict__ b1,
    const float* __restrict__ g1, const float* __restrict__ be1,
    const unsigned short* __restrict__ pk2, const float* __restrict__ b2,
    const float* __restrict__ g2, const float* __restrict__ be2,
    const int* __restrict__ nbr, const float* __restrict__ pc,
    float* __restrict__ outf) {
    __shared__ __align__(16) unsigned short bstage[16 * 1024];  // 32 KB
    __shared__ __align__(16) unsigned int hpk[64][132];         // 33 KB
    __shared__ float lnred[4][64][2];                           // 2 KB

    const int w = threadIdx.x >> 6, l = threadIdx.x & 63;
    const int lg = l >> 4, li = l & 15;
    const int ws4 = 4 * w;

    // per-rb row info: row = blockIdx.x*64 + rb*16 + li
    int nb[4];
    float rel[4][3];
#pragma unroll
    for (int rb = 0; rb < 4; ++rb) {
        int row_g = blockIdx.x * 64 + rb * 16 + li;
        int c = (blockIdx.x * 64 + rb * 16) / K;  // li never crosses a center
        int b = c >> 9;
        int n = nbr[row_g];
        nb[rb] = b * NPTS + n;
        const float* X = xyz + (size_t)nb[rb] * 3;
        const float* C = pc + (size_t)c * 3;
        rel[rb][0] = __fsub_rn(X[0], C[0]);
        rel[rb][1] = __fsub_rn(X[1], C[1]);
        rel[rb][2] = __fsub_rn(X[2], C[2]);
    }

    // ---------------- MLP1: [64 x 160] @ [160 x 64-slice] (bf16x3) --------
    f32x4 acc1[4][4];
#pragma unroll
    for (int rb = 0; rb < 4; ++rb)
#pragma unroll
        for (int ctl = 0; ctl < 4; ++ctl) acc1[rb][ctl] = (f32x4){0.f, 0.f, 0.f, 0.f};

#pragma unroll
    for (int ks = 0; ks < 5; ++ks) {
        // stage this wave's 4 B-frags (wave-private slots, no barrier needed)
#pragma unroll
        for (int ctl = 0; ctl < 4; ++ctl) {
            const unsigned short* src = pk1 + (size_t)((ws4 + ctl) * 5 + ks) * 1024;
            unsigned short* dst = bstage + (ws4 + ctl) * 1024;
            gload_lds16(src + (size_t)l * 8, dst);
            gload_lds16(src + 512 + (size_t)l * 8, dst + 512);
        }
        // build A fragments while loads are in flight
        s16x8 Ah[4], Al[4];
#pragma unroll
        for (int rb = 0; rb < 4; ++rb) {
            float v[8];
            if (ks < 4) {
                const float* src = pf + (size_t)nb[rb] * STEM + ks * 32 + lg * 8;
                float4 f0 = *(const float4*)src;
                float4 f1 = *(const float4*)(src + 4);
                v[0] = f0.x; v[1] = f0.y; v[2] = f0.z; v[3] = f0.w;
                v[4] = f1.x; v[5] = f1.y; v[6] = f1.z; v[7] = f1.w;
            } else {
#pragma unroll
                for (int j = 0; j < 8; ++j) {
                    int ch = lg * 8 + j;  // feature 128+ch
                    float val = 0.0f;
                    if (ch < 3) {
                        val = rel[rb][ch];
                    } else if (ch < 27) {
                        int rem = ch - 3;
                        int axis = rem >> 3, r8 = rem & 7;
                        int fi = (r8 < 4) ? r8 : r8 - 4;
                        float fr = expf(__fdiv_rn(-logf(10000.0f) * (float)fi, 3.0f));
                        float ang = rel[rb][axis] * fr;
                        val = (r8 < 4) ? sinf(ang) : cosf(ang);
                    }
                    v[j] = val;
                }
            }
            bsplit8(v, Ah[rb], Al[rb]);
        }
        asm volatile("s_waitcnt vmcnt(0)" ::: "memory");  // own B-stage landed
#pragma unroll
        for (int ctl = 0; ctl < 4; ++ctl) {
            const s16x8 Bh = *(const s16x8*)(bstage + (ws4 + ctl) * 1024 + l * 8);
            const s16x8 Bl = *(const s16x8*)(bstage + (ws4 + ctl) * 1024 + 512 + l * 8);
#pragma unroll
            for (int rb = 0; rb < 4; ++rb) {
                acc1[rb][ctl] = __builtin_amdgcn_mfma_f32_16x16x32_bf16(Ah[rb], Bh, acc1[rb][ctl], 0, 0, 0);
                acc1[rb][ctl] = __builtin_amdgcn_mfma_f32_16x16x32_bf16(Ah[rb], Bl, acc1[rb][ctl], 0, 0, 0);
                acc1[rb][ctl] = __builtin_amdgcn_mfma_f32_16x16x32_bf16(Al[rb], Bh, acc1[rb][ctl], 0, 0, 0);
            }
        }
    }

    // ---------------- bias + LN1 (cross-wave stats) + GELU -----------------
    float b1v[4], g1v[4], be1v[4];
#pragma unroll
    for (int ctl = 0; ctl < 4; ++ctl) {
        int col = w * 64 + ctl * 16 + li;
        b1v[ctl] = b1[col]; g1v[ctl] = g1[col]; be1v[ctl] = be1[col];
    }
#pragma unroll
    for (int rb = 0; rb < 4; ++rb)
#pragma unroll
        for (int reg = 0; reg < 4; ++reg) {
            float s = 0.f, ss = 0.f;
#pragma unroll
            for (int ctl = 0; ctl < 4; ++ctl) {
                float x = acc1[rb][ctl][reg] + b1v[ctl];
                s += x; ss = fmaf(x, x, ss);
            }
#pragma unroll
            for (int m = 1; m <= 8; m <<= 1) {
                s += __shfl_xor(s, m, 64);
                ss += __shfl_xor(ss, m, 64);
            }
            if (li == 0) {
                lnred[w][rb * 16 + lg * 4 + reg][0] = s;
                lnred[w][rb * 16 + lg * 4 + reg][1] = ss;
            }
        }
    __syncthreads();  // B1
#pragma unroll
    for (int rb = 0; rb < 4; ++rb)
#pragma unroll
        for (int reg = 0; reg < 4; ++reg) {
            int row = rb * 16 + lg * 4 + reg;
            float s = 0.f, ss = 0.f;
#pragma unroll
            for (int ww = 0; ww < 4; ++ww) {
                s += lnred[ww][row][0];
                ss += lnred[ww][row][1];
            }
            float mean = s * (1.0f / 256.0f);
            float var = ss * (1.0f / 256.0f) - mean * mean;
            float rs = rsqrtf(var + 1e-5f);
#pragma unroll
            for (int ctl = 0; ctl < 4; ++ctl) {
                float x = acc1[rb][ctl][reg] + b1v[ctl];
                float vv = (x - mean) * rs * g1v[ctl] + be1v[ctl];
                acc1[rb][ctl][reg] = 0.5f * vv * (1.0f + erff(vv * 0.70710678118654752f));
            }
        }

    // ---------------- MLP2: h parked to LDS in two 128-col halves ----------
    f32x4 acc2[4][4];
#pragma unroll
    for (int rb = 0; rb < 4; ++rb)
#pragma unroll
        for (int ctl = 0; ctl < 4; ++ctl) acc2[rb][ctl] = (f32x4){0.f, 0.f, 0.f, 0.f};

#pragma unroll
    for (int hh = 0; hh < 2; ++hh) {
        if ((w >> 1) == hh) {  // waves of this half park their h slice
#pragma unroll
            for (int rb = 0; rb < 4; ++rb)
#pragma unroll
                for (int ctl = 0; ctl < 4; ++ctl) {
                    unsigned w0, w1, w2, w3;
                    pkpair(acc1[rb][ctl][0], acc1[rb][ctl][1], w0, w1);
                    pkpair(acc1[rb][ctl][2], acc1[rb][ctl][3], w2, w3);
                    int kc = (w & 1) * 64 + ctl * 16 + li;
                    hpk[rb * 16 + lg * 4 + 0][kc] = w0;
                    hpk[rb * 16 + lg * 4 + 1][kc] = w1;
                    hpk[rb * 16 + lg * 4 + 2][kc] = w2;
                    hpk[rb * 16 + lg * 4 + 3][kc] = w3;
                }
        }
        __syncthreads();  // B2 / B4
#pragma unroll
        for (int q = 0; q < 4; ++q) {
            const int ksg = hh * 4 + q;
#pragma unroll
            for (int ctl = 0; ctl < 4; ++ctl) {
                const unsigned short* src = pk2 + (size_t)((ws4 + ctl) * 8 + ksg) * 1024;
                unsigned short* dst = bstage + (ws4 + ctl) * 1024;
                gload_lds16(src + (size_t)l * 8, dst);
                gload_lds16(src + 512 + (size_t)l * 8, dst + 512);
            }
            s16x8 Ah2[4], Al2[4];
#pragma unroll
            for (int rb = 0; rb < 4; ++rb) {
                const unsigned int* hp = &hpk[rb * 16 + li][q * 32 + lg * 8];
                int4 xa = *(const int4*)hp;
                int4 xb = *(const int4*)(hp + 4);
                unsigned x[8] = {(unsigned)xa.x, (unsigned)xa.y, (unsigned)xa.z, (unsigned)xa.w,
                                 (unsigned)xb.x, (unsigned)xb.y, (unsigned)xb.z, (unsigned)xb.w};
                union { s16x8 s; unsigned w[4]; } H, L;
#pragma unroll
                for (int p = 0; p < 4; ++p) {
                    H.w[p] = (x[2 * p] >> 16) | (x[2 * p + 1] & 0xffff0000u);
                    L.w[p] = (x[2 * p] & 0xffffu) | (x[2 * p + 1] << 16);
                }
                Ah2[rb] = H.s; Al2[rb] = L.s;
            }
            asm volatile("s_waitcnt vmcnt(0)" ::: "memory");
#pragma unroll
            for (int ctl = 0; ctl < 4; ++ctl) {
                const s16x8 Bh = *(const s16x8*)(bstage + (ws4 + ctl) * 1024 + l * 8);
                const s16x8 Bl = *(const s16x8*)(bstage + (ws4 + ctl) * 1024 + 512 + l * 8);
#pragma unroll
                for (int rb = 0; rb < 4; ++rb) {
                    acc2[rb][ctl] = __builtin_amdgcn_mfma_f32_16x16x32_bf16(Ah2[rb], Bh, acc2[rb][ctl], 0, 0, 0);
                    acc2[rb][ctl] = __builtin_amdgcn_mfma_f32_16x16x32_bf16(Ah2[rb], Bl, acc2[rb][ctl], 0, 0, 0);
                    acc2[rb][ctl] = __builtin_amdgcn_mfma_f32_16x16x32_bf16(Al2[rb], Bh, acc2[rb][ctl], 0, 0, 0);
                }
            }
        }
        if (hh == 0) __syncthreads();  // B3: half-0 reads done before overwrite
    }

    // ---------------- bias + LN2 (cross-wave stats) ------------------------
    float b2v[4], g2v[4], be2v[4];
#pragma unroll
    for (int ctl = 0; ctl < 4; ++ctl) {
        int col = w * 64 + ctl * 16 + li;
        b2v[ctl] = b2[col]; g2v[ctl] = g2[col]; be2v[ctl] = be2[col];
    }
#pragma unroll
    for (int rb = 0; rb < 4; ++rb)
#pragma unroll
        for (int reg = 0; reg < 4; ++reg) {
            float s = 0.f, ss = 0.f;
#pragma unroll
            for (int ctl = 0; ctl < 4; ++ctl) {
                float x = acc2[rb][ctl][reg] + b2v[ctl];
                s += x; ss = fmaf(x, x, ss);
            }
#pragma unroll
            for (int m = 1; m <= 8; m <<= 1) {
                s += __shfl_xor(s, m, 64);
                ss += __shfl_xor(ss, m, 64);
            }
            if (li == 0) {
                lnred[w][rb * 16 + lg * 4 + reg][0] = s;
                lnred[w][rb * 16 + lg * 4 + reg][1] = ss;
            }
        }
    __syncthreads();  // B5
#pragma unroll
    for (int rb = 0; rb < 4; ++rb)
#pragma unroll
        for (int reg = 0; reg < 4; ++reg) {
            int row = rb * 16 + lg * 4 + reg;
            float s = 0.f, ss = 0.f;
#pragma unroll
            for (int ww = 0; ww < 4; ++ww) {
                s += lnred[ww][row][0];
                ss += lnred[ww][row][1];
            }
            float mean = s * (1.0f / 256.0f);
            float var = ss * (1.0f / 256.0f) - mean * mean;
            float rs = rsqrtf(var + 1e-5f);
#pragma unroll
            for (int ctl = 0; ctl < 4; ++ctl) {
                float x = acc2[rb][ctl][reg] + b2v[ctl];
                acc2[rb][ctl][reg] = (x - mean) * rs * g2v[ctl] + be2v[ctl];
            }
        }

    // ---------------- max-pool over K rows per center, emit ----------------
    const int CPB = 64 / K;   // centers per block
    const int RBC = K / 16;   // 16-row groups per center
#pragma unroll
    for (int cg = 0; cg < CPB; ++cg)
#pragma unroll
        for (int ctl = 0; ctl < 4; ++ctl) {
            float mx = -3.4e38f;
#pragma unroll
            for (int rbl = 0; rbl < RBC; ++rbl) {
                int rb = cg * RBC + rbl;
#pragma unroll
                for (int reg = 0; reg < 4; ++reg) mx = fmaxf(mx, acc2[rb][ctl][reg]);
            }
            mx = fmaxf(mx, __shfl_xor(mx, 16, 64));
            mx = fmaxf(mx, __shfl_xor(mx, 32, 64));
            if (lg == 0)
                outf[(size_t)(blockIdx.x * CPB + cg) * TOK + w * 64 + ctl * 16 + li] = mx;
        }
}

// ---------------- Token MLP (unchanged, f32) -------------------------------
__global__ __launch_bounds__(256) void token_kernel(
    const float* __restrict__ pf,
    const float* __restrict__ tW1, const float* __restrict__ tb1,
    const float* __restrict__ tg1, const float* __restrict__ tbe1,
    const float* __restrict__ tW2, const float* __restrict__ tb2,
    const float* __restrict__ tg2, const float* __restrict__ tbe2,
    const int* __restrict__ center_idx, const float* __restrict__ pc,
    const float* __restrict__ sf0, const float* __restrict__ sf1,
    const float* __restrict__ sf2, float* __restrict__ out) {
    int bc = blockIdx.x;
    int b = bc >> 9;
    int t = threadIdx.x;
    __shared__ __align__(16) float tin[D_TOK];
    __shared__ float hh[TOK];
    __shared__ float red[8];
    int cidx = center_idx[bc];
    if (t < STEM) tin[t] = pf[((size_t)b * NPTS + cidx) * STEM + t];
    tin[128 + t] = sf0[(size_t)bc * TOK + t];
    tin[384 + t] = sf1[(size_t)bc * TOK + t];
    tin[640 + t] = sf2[(size_t)bc * TOK + t];
    if (t < 96) {
        int axis = t >> 5;
        int rem = t & 31;
        float c = pc[(size_t)bc * 3 + axis];
        int fi = (rem < 16) ? rem : rem - 16;
        float fr = expf(__fdiv_rn(-logf(10000.0f) * (float)fi, 15.0f));
        float ang = c * fr;
        tin[896 + t] = (rem < 16) ? sinf(ang) : cosf(ang);
    }
    __syncthreads();
    float acc = tb1[t];
    for (int i = 0; i < D_TOK; i += 4) {
        float4 x = *reinterpret_cast<const float4*>(&tin[i]);
        acc = fmaf(x.x, tW1[(i + 0) * TOK + t], acc);
        acc = fmaf(x.y, tW1[(i + 1) * TOK + t], acc);
        acc = fmaf(x.z, tW1[(i + 2) * TOK + t], acc);
        acc = fmaf(x.w, tW1[(i + 3) * TOK + t], acc);
    }
    int w = t >> 6, lane = t & 63;
    float s = acc, ss = acc * acc;
#pragma unroll
    for (int off = 32; off >= 1; off >>= 1) {
        s += __shfl_xor(s, off, 64);
        ss += __shfl_xor(ss, off, 64);
    }
    if (lane == 0) { red[w * 2] = s; red[w * 2 + 1] = ss; }
    __syncthreads();
    float S4 = red[0] + red[2] + red[4] + red[6];
    float SS4 = red[1] + red[3] + red[5] + red[7];
    float m = S4 * (1.0f / 256.0f);
    float var = SS4 * (1.0f / 256.0f) - m * m;
    float rs = rsqrtf(var + 1e-5f);
    float v = (acc - m) * rs * tg1[t] + tbe1[t];
    v = 0.5f * v * (1.0f + erff(v * 0.70710678118654752f));
    hh[t] = v;
    __syncthreads();
    float acc2 = tb2[t];
    for (int i = 0; i < TOK; i += 4) {
        float4 x = *reinterpret_cast<const float4*>(&hh[i]);
        acc2 = fmaf(x.x, tW2[(i + 0) * TOK + t], acc2);
        acc2 = fmaf(x.y, tW2[(i + 1) * TOK + t], acc2);
        acc2 = fmaf(x.z, tW2[(i + 2) * TOK + t], acc2);
        acc2 = fmaf(x.w, tW2[(i + 3) * TOK + t], acc2);
    }
    float s2 = acc2, ss2 = acc2 * acc2;
#pragma unroll
    for (int off = 32; off >= 1; off >>= 1) {
        s2 += __shfl_xor(s2, off, 64);
        ss2 += __shfl_xor(ss2, off, 64);
    }
    __syncthreads();
    if (lane == 0) { red[w * 2] = s2; red[w * 2 + 1] = ss2; }
    __syncthreads();
    float S42 = red[0] + red[2] + red[4] + red[6];
    float SS42 = red[1] + red[3] + red[5] + red[7];
    float m2 = S42 * (1.0f / 256.0f);
    float var2 = SS42 * (1.0f / 256.0f) - m2 * m2;
    float rs2 = rsqrtf(var2 + 1e-5f);
    float v2 = (acc2 - m2) * rs2 * tg2[t] + tbe2[t];
    out[(size_t)bc * TOK + t] = v2;
}

extern "C" void kernel_launch(void* const* d_in, const int* in_sizes, int n_in,
                              void* d_out, int out_size, void* d_ws, size_t ws_size,
                              hipStream_t stream) {
    const float* xyz  = (const float*)d_in[0];
    const float* pf   = (const float*)d_in[1];
    const float* sW1  = (const float*)d_in[2];
    const float* sb1  = (const float*)d_in[3];
    const float* sg1  = (const float*)d_in[4];
    const float* sbe1 = (const float*)d_in[5];
    const float* sW2  = (const float*)d_in[6];
    const float* sb2  = (const float*)d_in[7];
    const float* sg2  = (const float*)d_in[8];
    const float* sbe2 = (const float*)d_in[9];
    const float* tW1  = (const float*)d_in[10];
    const float* tb1  = (const float*)d_in[11];
    const float* tg1  = (const float*)d_in[12];
    const float* tbe1 = (const float*)d_in[13];
    const float* tW2  = (const float*)d_in[14];
    const float* tb2  = (const float*)d_in[15];
    const float* tg2  = (const float*)d_in[16];
    const float* tbe2 = (const float*)d_in[17];

    float* out_tok = (float*)d_out;
    float* out_pc  = out_tok + (size_t)BATCH * NCTR * TOK;

    char* ws = (char*)d_ws;
    int* center_idx = (int*)ws;   ws += (size_t)BATCH * NCTR * 4;
    float* pc_ws    = (float*)ws; ws += (size_t)BATCH * NCTR * 3 * 4;
    int* nbr0       = (int*)ws;   ws += (size_t)BATCH * NCTR * 16 * 4;
    int* nbr1       = (int*)ws;   ws += (size_t)BATCH * NCTR * 32 * 4;
    int* nbr2       = (int*)ws;   ws += (size_t)BATCH * NCTR * 64 * 4;
    float* sf0      = (float*)ws; ws += (size_t)BATCH * NCTR * TOK * 4;
    float* sf1      = (float*)ws; ws += (size_t)BATCH * NCTR * TOK * 4;
    float* sf2      = (float*)ws; ws += (size_t)BATCH * NCTR * TOK * 4;
    const size_t PK1_S = 16 * 5 * 64 * 16;   // ushorts per scale (W1)
    const size_t PK2_S = 16 * 8 * 64 * 16;   // ushorts per scale (W2)
    unsigned short* pkW1 = (unsigned short*)ws; ws += 3 * PK1_S * 2;
    unsigned short* pkW2 = (unsigned short*)ws; ws += 3 * PK2_S * 2;

    {
        dim3 gp1((16 * 5 * 64 + 255) / 256, 3);
        pack_w<<<gp1, 256, 0, stream>>>(sW1, pkW1, D_IN, 5);
        dim3 gp2((16 * 8 * 64 + 255) / 256, 3);
        pack_w<<<gp2, 256, 0, stream>>>(sW2, pkW2, TOK, 8);
    }

    fps_kernel<<<BATCH, 256, 0, stream>>>(xyz, center_idx, pc_ws, out_pc);

    ballq_kernel<16><<<BATCH * NCTR / 4, 256, 0, stream>>>(xyz, pc_ws, nbr0, (float)(0.1 * 0.1));
    ballq_kernel<32><<<BATCH * NCTR / 4, 256, 0, stream>>>(xyz, pc_ws, nbr1, (float)(0.2 * 0.2));
    ballq_kernel<64><<<BATCH * NCTR / 4, 256, 0, stream>>>(xyz, pc_ws, nbr2, (float)(0.4 * 0.4));

    // 64 rows per block
    scale_mfma<16><<<(BATCH * NCTR * 16) / 64, 256, 0, stream>>>(
        xyz, pf, pkW1 + 0 * PK1_S, sb1 + 0 * TOK, sg1 + 0 * TOK, sbe1 + 0 * TOK,
        pkW2 + 0 * PK2_S, sb2 + 0 * TOK, sg2 + 0 * TOK, sbe2 + 0 * TOK,
        nbr0, pc_ws, sf0);
    scale_mfma<32><<<(BATCH * NCTR * 32) / 64, 256, 0, stream>>>(
        xyz, pf, pkW1 + 1 * PK1_S, sb1 + 1 * TOK, sg1 + 1 * TOK, sbe1 + 1 * TOK,
        pkW2 + 1 * PK2_S, sb2 + 1 * TOK, sg2 + 1 * TOK, sbe2 + 1 * TOK,
        nbr1, pc_ws, sf1);
    scale_mfma<64><<<(BATCH * NCTR * 64) / 64, 256, 0, stream>>>(
        xyz, pf, pkW1 + 2 * PK1_S, sb1 + 2 * TOK, sg1 + 2 * TOK, sbe1 + 2 * TOK,
        pkW2 + 2 * PK2_S, sb2 + 2 * TOK, sg2 + 2 * TOK, sbe2 + 2 * TOK,
        nbr2, pc_ws, sf2);

    token_kernel<<<BATCH * NCTR, 256, 0, stream>>>(
        pf, tW1, tb1, tg1, tbe1, tW2, tb2, tg2, tbe2,
        center_idx, pc_ws, sf0, sf1, sf2, out_tok);
}

// Round 5
// 1727.285 us; speedup vs baseline: 4.7314x; 1.4477x over previous
//
#include <hip/hip_runtime.h>
#include <math.h>

#define BATCH 16
#define NPTS  4096
#define NCTR  512
#define STEM  128
#define TOK   256
#define D_IN  155   // 128 + 3 + 24
#define D_TOK 992   // 128 + 3*256 + 96

typedef short s16x8 __attribute__((ext_vector_type(8)));
typedef float f32x4 __attribute__((ext_vector_type(4)));

__constant__ float FR15[16] = {
    1.0f, 0.5411695265464638f, 0.2928644487857941f, 0.15848931670188904f,
    0.08576958626508713f, 0.04641588851809502f, 0.02511886507272720f, 0.01359356392547488f,
    0.007356422487646341f, 0.003981071710586548f, 0.002154434798285365f, 0.001165914465673268f,
    0.0006309573450125754f, 0.0003414548910222948f, 0.0001847849769866168f, 0.0001f};

__device__ __forceinline__ unsigned short f2bf(float f) {
    unsigned u = __float_as_uint(f);
    u += 0x7FFF + ((u >> 16) & 1);
    return (unsigned short)(u >> 16);
}
__device__ __forceinline__ float bf2f(unsigned short b) {
    return __uint_as_float(((unsigned)b) << 16);
}

// split 8 f32 -> hi/lo bf16 fragments via v_cvt_pk_bf16_f32 (RNE)
__device__ __forceinline__ void bsplit8(const float* v, s16x8& hi, s16x8& lo) {
    union { s16x8 s; unsigned w[4]; } H, L;
#pragma unroll
    for (int p = 0; p < 4; ++p) {
        unsigned hp, lp;
        asm("v_cvt_pk_bf16_f32 %0, %1, %2" : "=v"(hp) : "v"(v[2 * p]), "v"(v[2 * p + 1]));
        float r0 = v[2 * p]     - __uint_as_float(hp << 16);
        float r1 = v[2 * p + 1] - __uint_as_float(hp & 0xffff0000u);
        asm("v_cvt_pk_bf16_f32 %0, %1, %2" : "=v"(lp) : "v"(r0), "v"(r1));
        H.w[p] = hp; L.w[p] = lp;
    }
    hi = H.s; lo = L.s;
}

// pack two f32 into two (hi16|lo16) u32 words
__device__ __forceinline__ void pkpair(float v0, float v1, unsigned& w0, unsigned& w1) {
    unsigned hp, lp;
    asm("v_cvt_pk_bf16_f32 %0, %1, %2" : "=v"(hp) : "v"(v0), "v"(v1));
    float r0 = v0 - __uint_as_float(hp << 16);
    float r1 = v1 - __uint_as_float(hp & 0xffff0000u);
    asm("v_cvt_pk_bf16_f32 %0, %1, %2" : "=v"(lp) : "v"(r0), "v"(r1));
    w0 = (hp << 16) | (lp & 0xffffu);
    w1 = (hp & 0xffff0000u) | (lp >> 16);
}

// B-fragment direct load: global (L2-hot) -> VGPR, 16B hi + 16B lo per lane
__device__ __forceinline__ void loadB(const unsigned short* __restrict__ pk,
                                      int frag, int l, s16x8& bh, s16x8& bl) {
    const unsigned short* p = pk + (size_t)frag * 1024 + (size_t)l * 8;
    bh = *(const s16x8*)p;
    bl = *(const s16x8*)(p + 512);
}

// fast exact-GELU: A&S 7.1.26 erf (|abs err| < 2e-7)
__device__ __forceinline__ float gelu_exact(float x) {
    float z = x * 0.70710678118654752f;
    float a = fabsf(z);
    float t = __builtin_amdgcn_rcpf(fmaf(0.3275911f, a, 1.0f));
    float p = fmaf(1.061405429f, t, -1.453152027f);
    p = fmaf(p, t, 1.421413741f);
    p = fmaf(p, t, -0.284496736f);
    p = fmaf(p, t, 0.254829592f);
    p = p * t;
    float e = __expf(-z * z);
    float y = fmaf(-p, e, 1.0f);
    y = (z < 0.0f) ? -y : y;
    return 0.5f * x * (1.0f + y);
}

// exact, non-contracted squared distance to match numpy f32 rounding
__device__ __forceinline__ float sq3(float ax, float ay, float az,
                                     float bx, float by, float bz) {
    float dx = __fsub_rn(ax, bx);
    float dy = __fsub_rn(ay, by);
    float dz = __fsub_rn(az, bz);
    float d = __fmul_rn(dx, dx);
    d = __fadd_rn(d, __fmul_rn(dy, dy));
    d = __fadd_rn(d, __fmul_rn(dz, dz));
    return d;
}

// ---------------- FPS (unchanged, index-exact) -----------------------------
__global__ __launch_bounds__(256) void fps_kernel(const float* __restrict__ xyz,
                                                  int* __restrict__ center_idx,
                                                  float* __restrict__ pc_ws,
                                                  float* __restrict__ pc_out) {
    int b = blockIdx.x;
    int t = threadIdx.x;
    const float* X = xyz + (size_t)b * NPTS * 3;
    float px[16], py[16], pz[16], dist[16];
#pragma unroll
    for (int j = 0; j < 16; ++j) {
        int i = t + 256 * j;
        px[j] = X[i * 3 + 0];
        py[j] = X[i * 3 + 1];
        pz[j] = X[i * 3 + 2];
        dist[j] = 1e10f;
    }
    __shared__ float sc[3];
    __shared__ int sfar;
    __shared__ float swv[4];
    __shared__ int swi[4];
    int far = 0;
    for (int s = 0; s < NCTR; ++s) {
        if (t == 0) {
            float cx = X[far * 3], cy = X[far * 3 + 1], cz = X[far * 3 + 2];
            sc[0] = cx; sc[1] = cy; sc[2] = cz;
            center_idx[b * NCTR + s] = far;
            size_t po = (size_t)(b * NCTR + s) * 3;
            pc_ws[po] = cx; pc_ws[po + 1] = cy; pc_ws[po + 2] = cz;
            pc_out[po] = cx; pc_out[po + 1] = cy; pc_out[po + 2] = cz;
        }
        __syncthreads();
        float cx = sc[0], cy = sc[1], cz = sc[2];
        float bv = -1.0f;
        int bi = 0;
#pragma unroll
        for (int j = 0; j < 16; ++j) {
            float d = sq3(px[j], py[j], pz[j], cx, cy, cz);
            float nd = fminf(dist[j], d);
            dist[j] = nd;
            if (nd > bv) { bv = nd; bi = t + 256 * j; }
        }
#pragma unroll
        for (int off = 32; off >= 1; off >>= 1) {
            float ov = __shfl_xor(bv, off, 64);
            int   oi = __shfl_xor(bi, off, 64);
            if (ov > bv || (ov == bv && oi < bi)) { bv = ov; bi = oi; }
        }
        if ((t & 63) == 0) { swv[t >> 6] = bv; swi[t >> 6] = bi; }
        __syncthreads();
        if (t == 0) {
            for (int w2 = 1; w2 < 4; ++w2) {
                float ov = swv[w2]; int oi = swi[w2];
                if (ov > bv || (ov == bv && oi < bi)) { bv = ov; bi = oi; }
            }
            sfar = bi;
        }
        __syncthreads();
        far = sfar;
    }
}

// ---------------- Ball query (unchanged) ----------------------------------
template <int K>
__global__ __launch_bounds__(256) void ballq_kernel(const float* __restrict__ xyz,
                                                    const float* __restrict__ pc,
                                                    int* __restrict__ nbr,
                                                    float rr) {
    int cid = blockIdx.x * 4 + (threadIdx.x >> 6);
    int lane = threadIdx.x & 63;
    int b = cid >> 9;
    const float* X = xyz + (size_t)b * NPTS * 3;
    float cx = pc[(size_t)cid * 3 + 0];
    float cy = pc[(size_t)cid * 3 + 1];
    float cz = pc[(size_t)cid * 3 + 2];
    int cnt = 0, first = 0;
    bool have_first = false;
    long long base = (long long)cid * K;
    for (int it = 0; it < NPTS / 64; ++it) {
        int i = it * 64 + lane;
        float d = sq3(cx, cy, cz, X[i * 3], X[i * 3 + 1], X[i * 3 + 2]);
        bool ok = d <= rr;
        unsigned long long mask = __ballot(ok);
        if (!have_first && mask) {
            first = it * 64 + (int)__builtin_ctzll(mask);
            have_first = true;
        }
        int pos = cnt + (int)__popcll(mask & ((1ull << lane) - 1ull));
        if (ok && pos < K) nbr[base + pos] = i;
        cnt += (int)__popcll(mask);
        if (cnt >= K) break;
    }
    int fill = cnt < K ? cnt : K;
    for (int j = fill + lane; j < K; j += 64) nbr[base + j] = first;
}

// ---------------- Weight pack: hi-plane/lo-plane bf16 MFMA B-frags --------
__global__ __launch_bounds__(256) void pack_w(const float* __restrict__ Wbase,
                                              unsigned short* __restrict__ out,
                                              int Kdim, int KS) {
    int s = blockIdx.y;
    const float* W = Wbase + (size_t)s * Kdim * TOK;
    unsigned short* o = out + (size_t)s * 16 * KS * 64 * 16;
    int tid = blockIdx.x * 256 + threadIdx.x;
    if (tid >= 16 * KS * 64) return;
    int lane = tid & 63;
    int frag = tid >> 6;
    int ks = frag % KS;
    int ct = frag / KS;
    int col = ct * 16 + (lane & 15);
    int k0 = ks * 32 + (lane >> 4) * 8;
    unsigned short* hi = o + (size_t)frag * 1024 + lane * 8;
    unsigned short* lo = hi + 512;
#pragma unroll
    for (int j = 0; j < 8; ++j) {
        int k = k0 + j;
        float v = (k < Kdim) ? W[(size_t)k * TOK + col] : 0.0f;
        unsigned short h = f2bf(v);
        hi[j] = h;
        lo[j] = f2bf(v - bf2f(h));
    }
}

// ---------------- Per-scale grouped MLP via bf16x3 MFMA --------------------
// Block = 64 rows x 256 cols; wave w owns cols [64w, 64w+64). acc1 dies
// before acc2 is born (full h park in LDS) -> everything fits in arch VGPRs.
// B-fragments read directly global->VGPR (L2-hot, no LDS staging).
template <int K>
__global__ __launch_bounds__(256, 2) void scale_mfma(
    const float* __restrict__ xyz, const float* __restrict__ pf,
    const unsigned short* __restrict__ pk1, const float* __restrict__ b1,
    const float* __restrict__ g1, const float* __restrict__ be1,
    const unsigned short* __restrict__ pk2, const float* __restrict__ b2,
    const float* __restrict__ g2, const float* __restrict__ be2,
    const int* __restrict__ nbr, const float* __restrict__ pc,
    float* __restrict__ outf) {
    __shared__ unsigned int hpk[64][260];   // 65 KB: full packed-bf16 h
    __shared__ float lnred[4][64][2];       // 2 KB
    const int w = threadIdx.x >> 6, l = threadIdx.x & 63;
    const int lg = l >> 4, li = l & 15;
    const int ws4 = 4 * w;

    int nb[4];
    float relx[4], rely[4], relz[4];
#pragma unroll
    for (int rb = 0; rb < 4; ++rb) {
        int row_g = blockIdx.x * 64 + rb * 16 + li;
        int c = (blockIdx.x * 64 + rb * 16) / K;
        int b = c >> 9;
        int n = nbr[row_g];
        nb[rb] = b * NPTS + n;
        const float* X = xyz + (size_t)nb[rb] * 3;
        const float* C = pc + (size_t)c * 3;
        relx[rb] = __fsub_rn(X[0], C[0]);
        rely[rb] = __fsub_rn(X[1], C[1]);
        relz[rb] = __fsub_rn(X[2], C[2]);
    }

    // ---------------- MLP1: [64 x 160] @ [160 x 64-slice] (bf16x3) --------
    f32x4 acc1[4][4];
#pragma unroll
    for (int rb = 0; rb < 4; ++rb)
#pragma unroll
        for (int ctl = 0; ctl < 4; ++ctl) acc1[rb][ctl] = (f32x4){0.f, 0.f, 0.f, 0.f};

#pragma unroll
    for (int ks = 0; ks < 5; ++ks) {
        s16x8 Bh[4], Bl[4];
#pragma unroll
        for (int ctl = 0; ctl < 4; ++ctl)
            loadB(pk1, (ws4 + ctl) * 5 + ks, l, Bh[ctl], Bl[ctl]);
        s16x8 Ah[4], Al[4];
#pragma unroll
        for (int rb = 0; rb < 4; ++rb) {
            float v[8];
            if (ks < 4) {
                const float* src = pf + (size_t)nb[rb] * STEM + ks * 32 + lg * 8;
                float4 f0 = *(const float4*)src;
                float4 f1 = *(const float4*)(src + 4);
                v[0] = f0.x; v[1] = f0.y; v[2] = f0.z; v[3] = f0.w;
                v[4] = f1.x; v[5] = f1.y; v[6] = f1.z; v[7] = f1.w;
            } else {
#pragma unroll
                for (int j = 0; j < 8; ++j) {
                    int ch = lg * 8 + j;  // feature 128+ch
                    float val = 0.0f;
                    if (ch < 3) {
                        val = (ch == 0) ? relx[rb] : ((ch == 1) ? rely[rb] : relz[rb]);
                    } else if (ch < 27) {
                        int rem = ch - 3;
                        int axis = rem >> 3, r8 = rem & 7;
                        int fi = (r8 < 4) ? r8 : r8 - 4;
                        float fr = (fi == 0) ? 1.0f
                                  : (fi == 1) ? 0.046415888336127795f
                                  : (fi == 2) ? 0.0021544346900318843f : 1e-4f;
                        float rl = (axis == 0) ? relx[rb] : ((axis == 1) ? rely[rb] : relz[rb]);
                        float ang = rl * fr;
                        val = (r8 < 4) ? __sinf(ang) : __cosf(ang);
                    }
                    v[j] = val;
                }
            }
            bsplit8(v, Ah[rb], Al[rb]);
        }
#pragma unroll
        for (int ctl = 0; ctl < 4; ++ctl)
#pragma unroll
            for (int rb = 0; rb < 4; ++rb) {
                acc1[rb][ctl] = __builtin_amdgcn_mfma_f32_16x16x32_bf16(Ah[rb], Bh[ctl], acc1[rb][ctl], 0, 0, 0);
                acc1[rb][ctl] = __builtin_amdgcn_mfma_f32_16x16x32_bf16(Ah[rb], Bl[ctl], acc1[rb][ctl], 0, 0, 0);
                acc1[rb][ctl] = __builtin_amdgcn_mfma_f32_16x16x32_bf16(Al[rb], Bh[ctl], acc1[rb][ctl], 0, 0, 0);
            }
    }

    // ---------------- bias + LN1 (cross-wave stats) + GELU -----------------
    {
        float b1v[4], g1v[4], be1v[4];
#pragma unroll
        for (int ctl = 0; ctl < 4; ++ctl) {
            int col = w * 64 + ctl * 16 + li;
            b1v[ctl] = b1[col]; g1v[ctl] = g1[col]; be1v[ctl] = be1[col];
        }
#pragma unroll
        for (int rb = 0; rb < 4; ++rb)
#pragma unroll
            for (int reg = 0; reg < 4; ++reg) {
                float s = 0.f, ss = 0.f;
#pragma unroll
                for (int ctl = 0; ctl < 4; ++ctl) {
                    float x = acc1[rb][ctl][reg] + b1v[ctl];
                    s += x; ss = fmaf(x, x, ss);
                }
#pragma unroll
                for (int m = 1; m <= 8; m <<= 1) {
                    s += __shfl_xor(s, m, 64);
                    ss += __shfl_xor(ss, m, 64);
                }
                if (li == 0) {
                    lnred[w][rb * 16 + lg * 4 + reg][0] = s;
                    lnred[w][rb * 16 + lg * 4 + reg][1] = ss;
                }
            }
        __syncthreads();  // B1
#pragma unroll
        for (int rb = 0; rb < 4; ++rb)
#pragma unroll
            for (int reg = 0; reg < 4; ++reg) {
                int row = rb * 16 + lg * 4 + reg;
                float s = lnred[0][row][0] + lnred[1][row][0] + lnred[2][row][0] + lnred[3][row][0];
                float ss = lnred[0][row][1] + lnred[1][row][1] + lnred[2][row][1] + lnred[3][row][1];
                float mean = s * (1.0f / 256.0f);
                float var = ss * (1.0f / 256.0f) - mean * mean;
                float rs = rsqrtf(var + 1e-5f);
#pragma unroll
                for (int ctl = 0; ctl < 4; ++ctl) {
                    float x = acc1[rb][ctl][reg] + b1v[ctl];
                    acc1[rb][ctl][reg] = gelu_exact((x - mean) * rs * g1v[ctl] + be1v[ctl]);
                }
            }
    }

    // ---------------- park FULL h (packed hi|lo u32); acc1 dies here -------
#pragma unroll
    for (int rb = 0; rb < 4; ++rb)
#pragma unroll
        for (int ctl = 0; ctl < 4; ++ctl) {
            unsigned w0, w1, w2, w3;
            pkpair(acc1[rb][ctl][0], acc1[rb][ctl][1], w0, w1);
            pkpair(acc1[rb][ctl][2], acc1[rb][ctl][3], w2, w3);
            int r0 = rb * 16 + lg * 4;
            int kc = w * 64 + ctl * 16 + li;
            hpk[r0 + 0][kc] = w0; hpk[r0 + 1][kc] = w1;
            hpk[r0 + 2][kc] = w2; hpk[r0 + 3][kc] = w3;
        }
    __syncthreads();  // B2

    // ---------------- MLP2: [64 x 256] @ [256 x 64-slice] (bf16x3) ---------
    f32x4 acc2[4][4];
#pragma unroll
    for (int rb = 0; rb < 4; ++rb)
#pragma unroll
        for (int ctl = 0; ctl < 4; ++ctl) acc2[rb][ctl] = (f32x4){0.f, 0.f, 0.f, 0.f};

#pragma unroll
    for (int q = 0; q < 8; ++q) {
        s16x8 Bh[4], Bl[4];
#pragma unroll
        for (int ctl = 0; ctl < 4; ++ctl)
            loadB(pk2, (ws4 + ctl) * 8 + q, l, Bh[ctl], Bl[ctl]);
#pragma unroll
        for (int rb = 0; rb < 4; ++rb) {
            const unsigned int* hp = &hpk[rb * 16 + li][q * 32 + lg * 8];
            int4 xa = *(const int4*)hp;
            int4 xb = *(const int4*)(hp + 4);
            unsigned x[8] = {(unsigned)xa.x, (unsigned)xa.y, (unsigned)xa.z, (unsigned)xa.w,
                             (unsigned)xb.x, (unsigned)xb.y, (unsigned)xb.z, (unsigned)xb.w};
            union { s16x8 s; unsigned w[4]; } H, L;
#pragma unroll
            for (int p = 0; p < 4; ++p) {
                H.w[p] = (x[2 * p] >> 16) | (x[2 * p + 1] & 0xffff0000u);
                L.w[p] = (x[2 * p] & 0xffffu) | (x[2 * p + 1] << 16);
            }
#pragma unroll
            for (int ctl = 0; ctl < 4; ++ctl) {
                acc2[rb][ctl] = __builtin_amdgcn_mfma_f32_16x16x32_bf16(H.s, Bh[ctl], acc2[rb][ctl], 0, 0, 0);
                acc2[rb][ctl] = __builtin_amdgcn_mfma_f32_16x16x32_bf16(H.s, Bl[ctl], acc2[rb][ctl], 0, 0, 0);
                acc2[rb][ctl] = __builtin_amdgcn_mfma_f32_16x16x32_bf16(L.s, Bh[ctl], acc2[rb][ctl], 0, 0, 0);
            }
        }
    }

    // ---------------- bias + LN2 (cross-wave stats) ------------------------
    float b2v[4], g2v[4], be2v[4];
#pragma unroll
    for (int ctl = 0; ctl < 4; ++ctl) {
        int col = w * 64 + ctl * 16 + li;
        b2v[ctl] = b2[col]; g2v[ctl] = g2[col]; be2v[ctl] = be2[col];
    }
#pragma unroll
    for (int rb = 0; rb < 4; ++rb)
#pragma unroll
        for (int reg = 0; reg < 4; ++reg) {
            float s = 0.f, ss = 0.f;
#pragma unroll
            for (int ctl = 0; ctl < 4; ++ctl) {
                float x = acc2[rb][ctl][reg] + b2v[ctl];
                s += x; ss = fmaf(x, x, ss);
            }
#pragma unroll
            for (int m = 1; m <= 8; m <<= 1) {
                s += __shfl_xor(s, m, 64);
                ss += __shfl_xor(ss, m, 64);
            }
            if (li == 0) {
                lnred[w][rb * 16 + lg * 4 + reg][0] = s;
                lnred[w][rb * 16 + lg * 4 + reg][1] = ss;
            }
        }
    __syncthreads();  // B3
#pragma unroll
    for (int rb = 0; rb < 4; ++rb)
#pragma unroll
        for (int reg = 0; reg < 4; ++reg) {
            int row = rb * 16 + lg * 4 + reg;
            float s = lnred[0][row][0] + lnred[1][row][0] + lnred[2][row][0] + lnred[3][row][0];
            float ss = lnred[0][row][1] + lnred[1][row][1] + lnred[2][row][1] + lnred[3][row][1];
            float mean = s * (1.0f / 256.0f);
            float var = ss * (1.0f / 256.0f) - mean * mean;
            float rs = rsqrtf(var + 1e-5f);
#pragma unroll
            for (int ctl = 0; ctl < 4; ++ctl) {
                float x = acc2[rb][ctl][reg] + b2v[ctl];
                acc2[rb][ctl][reg] = (x - mean) * rs * g2v[ctl] + be2v[ctl];
            }
        }

    // ---------------- max-pool over K rows per center, emit ----------------
    const int CPB = 64 / K;
    const int RBC = K / 16;
#pragma unroll
    for (int cg = 0; cg < CPB; ++cg)
#pragma unroll
        for (int ctl = 0; ctl < 4; ++ctl) {
            float mx = -3.4e38f;
#pragma unroll
            for (int rbl = 0; rbl < RBC; ++rbl) {
                int rb = cg * RBC + rbl;
#pragma unroll
                for (int reg = 0; reg < 4; ++reg) mx = fmaxf(mx, acc2[rb][ctl][reg]);
            }
            mx = fmaxf(mx, __shfl_xor(mx, 16, 64));
            mx = fmaxf(mx, __shfl_xor(mx, 32, 64));
            if (lg == 0)
                outf[(size_t)(blockIdx.x * CPB + cg) * TOK + w * 64 + ctl * 16 + li] = mx;
        }
}

// ---------------- Token input build ----------------------------------------
__global__ __launch_bounds__(256) void tok_build(
    const float* __restrict__ pf, const int* __restrict__ center_idx,
    const float* __restrict__ pc, const float* __restrict__ sf0,
    const float* __restrict__ sf1, const float* __restrict__ sf2,
    float* __restrict__ ti) {
    int bc = blockIdx.x;
    int b = bc >> 9;
    int t = threadIdx.x;
    float* row = ti + (size_t)bc * D_TOK;
    int cidx = center_idx[bc];
    if (t < STEM) row[t] = pf[((size_t)b * NPTS + cidx) * STEM + t];
    row[128 + t] = sf0[(size_t)bc * TOK + t];
    row[384 + t] = sf1[(size_t)bc * TOK + t];
    row[640 + t] = sf2[(size_t)bc * TOK + t];
    if (t < 96) {
        int axis = t >> 5, rem = t & 31;
        float c = pc[(size_t)bc * 3 + axis];
        int fi = (rem < 16) ? rem : rem - 16;
        float ang = c * FR15[fi];
        row[896 + t] = (rem < 16) ? __sinf(ang) : __cosf(ang);
    }
}

// ---------------- Token MLP via bf16x3 MFMA: 32 rows/block -----------------
__global__ __launch_bounds__(256, 2) void token_mfma(
    const float* __restrict__ ti,
    const unsigned short* __restrict__ pk1, const float* __restrict__ b1,
    const float* __restrict__ g1, const float* __restrict__ be1,
    const unsigned short* __restrict__ pk2, const float* __restrict__ b2,
    const float* __restrict__ g2, const float* __restrict__ be2,
    float* __restrict__ out) {
    __shared__ unsigned int hpk[32][260];
    __shared__ float lnred[4][32][2];
    const int w = threadIdx.x >> 6, l = threadIdx.x & 63;
    const int lg = l >> 4, li = l & 15;
    const int ws4 = 4 * w;
    const int rowbase = blockIdx.x * 32;

    f32x4 acc1[2][4];
#pragma unroll
    for (int rb = 0; rb < 2; ++rb)
#pragma unroll
        for (int ctl = 0; ctl < 4; ++ctl) acc1[rb][ctl] = (f32x4){0.f, 0.f, 0.f, 0.f};

#pragma unroll 2
    for (int ks = 0; ks < 31; ++ks) {
        s16x8 Bh[4], Bl[4];
#pragma unroll
        for (int ctl = 0; ctl < 4; ++ctl)
            loadB(pk1, (ws4 + ctl) * 31 + ks, l, Bh[ctl], Bl[ctl]);
        s16x8 Ah[2], Al[2];
#pragma unroll
        for (int rb = 0; rb < 2; ++rb) {
            const float* src = ti + (size_t)(rowbase + rb * 16 + li) * D_TOK + ks * 32 + lg * 8;
            float4 f0 = *(const float4*)src;
            float4 f1 = *(const float4*)(src + 4);
            float v[8] = {f0.x, f0.y, f0.z, f0.w, f1.x, f1.y, f1.z, f1.w};
            bsplit8(v, Ah[rb], Al[rb]);
        }
#pragma unroll
        for (int ctl = 0; ctl < 4; ++ctl)
#pragma unroll
            for (int rb = 0; rb < 2; ++rb) {
                acc1[rb][ctl] = __builtin_amdgcn_mfma_f32_16x16x32_bf16(Ah[rb], Bh[ctl], acc1[rb][ctl], 0, 0, 0);
                acc1[rb][ctl] = __builtin_amdgcn_mfma_f32_16x16x32_bf16(Ah[rb], Bl[ctl], acc1[rb][ctl], 0, 0, 0);
                acc1[rb][ctl] = __builtin_amdgcn_mfma_f32_16x16x32_bf16(Al[rb], Bh[ctl], acc1[rb][ctl], 0, 0, 0);
            }
    }

    // bias + LN1 + GELU
    {
        float b1v[4], g1v[4], be1v[4];
#pragma unroll
        for (int ctl = 0; ctl < 4; ++ctl) {
            int col = w * 64 + ctl * 16 + li;
            b1v[ctl] = b1[col]; g1v[ctl] = g1[col]; be1v[ctl] = be1[col];
        }
#pragma unroll
        for (int rb = 0; rb < 2; ++rb)
#pragma unroll
            for (int reg = 0; reg < 4; ++reg) {
                float s = 0.f, ss = 0.f;
#pragma unroll
                for (int ctl = 0; ctl < 4; ++ctl) {
                    float x = acc1[rb][ctl][reg] + b1v[ctl];
                    s += x; ss = fmaf(x, x, ss);
                }
#pragma unroll
                for (int m = 1; m <= 8; m <<= 1) {
                    s += __shfl_xor(s, m, 64);
                    ss += __shfl_xor(ss, m, 64);
                }
                if (li == 0) {
                    lnred[w][rb * 16 + lg * 4 + reg][0] = s;
                    lnred[w][rb * 16 + lg * 4 + reg][1] = ss;
                }
            }
        __syncthreads();
#pragma unroll
        for (int rb = 0; rb < 2; ++rb)
#pragma unroll
            for (int reg = 0; reg < 4; ++reg) {
                int row = rb * 16 + lg * 4 + reg;
                float s = lnred[0][row][0] + lnred[1][row][0] + lnred[2][row][0] + lnred[3][row][0];
                float ss = lnred[0][row][1] + lnred[1][row][1] + lnred[2][row][1] + lnred[3][row][1];
                float mean = s * (1.0f / 256.0f);
                float var = ss * (1.0f / 256.0f) - mean * mean;
                float rs = rsqrtf(var + 1e-5f);
#pragma unroll
                for (int ctl = 0; ctl < 4; ++ctl) {
                    float x = acc1[rb][ctl][reg] + b1v[ctl];
                    acc1[rb][ctl][reg] = gelu_exact((x - mean) * rs * g1v[ctl] + be1v[ctl]);
                }
            }
    }

    // park h, acc1 dies
#pragma unroll
    for (int rb = 0; rb < 2; ++rb)
#pragma unroll
        for (int ctl = 0; ctl < 4; ++ctl) {
            unsigned w0, w1, w2, w3;
            pkpair(acc1[rb][ctl][0], acc1[rb][ctl][1], w0, w1);
            pkpair(acc1[rb][ctl][2], acc1[rb][ctl][3], w2, w3);
            int r0 = rb * 16 + lg * 4;
            int kc = w * 64 + ctl * 16 + li;
            hpk[r0 + 0][kc] = w0; hpk[r0 + 1][kc] = w1;
            hpk[r0 + 2][kc] = w2; hpk[r0 + 3][kc] = w3;
        }
    __syncthreads();

    // MLP2
    f32x4 acc2[2][4];
#pragma unroll
    for (int rb = 0; rb < 2; ++rb)
#pragma unroll
        for (int ctl = 0; ctl < 4; ++ctl) acc2[rb][ctl] = (f32x4){0.f, 0.f, 0.f, 0.f};
#pragma unroll
    for (int q = 0; q < 8; ++q) {
        s16x8 Bh[4], Bl[4];
#pragma unroll
        for (int ctl = 0; ctl < 4; ++ctl)
            loadB(pk2, (ws4 + ctl) * 8 + q, l, Bh[ctl], Bl[ctl]);
#pragma unroll
        for (int rb = 0; rb < 2; ++rb) {
            const unsigned int* hp = &hpk[rb * 16 + li][q * 32 + lg * 8];
            int4 xa = *(const int4*)hp;
            int4 xb = *(const int4*)(hp + 4);
            unsigned x[8] = {(unsigned)xa.x, (unsigned)xa.y, (unsigned)xa.z, (unsigned)xa.w,
                             (unsigned)xb.x, (unsigned)xb.y, (unsigned)xb.z, (unsigned)xb.w};
            union { s16x8 s; unsigned w[4]; } H, L;
#pragma unroll
            for (int p = 0; p < 4; ++p) {
                H.w[p] = (x[2 * p] >> 16) | (x[2 * p + 1] & 0xffff0000u);
                L.w[p] = (x[2 * p] & 0xffffu) | (x[2 * p + 1] << 16);
            }
#pragma unroll
            for (int ctl = 0; ctl < 4; ++ctl) {
                acc2[rb][ctl] = __builtin_amdgcn_mfma_f32_16x16x32_bf16(H.s, Bh[ctl], acc2[rb][ctl], 0, 0, 0);
                acc2[rb][ctl] = __builtin_amdgcn_mfma_f32_16x16x32_bf16(H.s, Bl[ctl], acc2[rb][ctl], 0, 0, 0);
                acc2[rb][ctl] = __builtin_amdgcn_mfma_f32_16x16x32_bf16(L.s, Bh[ctl], acc2[rb][ctl], 0, 0, 0);
            }
        }
    }

    // bias + LN2 + write
    float b2v[4], g2v[4], be2v[4];
#pragma unroll
    for (int ctl = 0; ctl < 4; ++ctl) {
        int col = w * 64 + ctl * 16 + li;
        b2v[ctl] = b2[col]; g2v[ctl] = g2[col]; be2v[ctl] = be2[col];
    }
#pragma unroll
    for (int rb = 0; rb < 2; ++rb)
#pragma unroll
        for (int reg = 0; reg < 4; ++reg) {
            float s = 0.f, ss = 0.f;
#pragma unroll
            for (int ctl = 0; ctl < 4; ++ctl) {
                float x = acc2[rb][ctl][reg] + b2v[ctl];
                s += x; ss = fmaf(x, x, ss);
            }
#pragma unroll
            for (int m = 1; m <= 8; m <<= 1) {
                s += __shfl_xor(s, m, 64);
                ss += __shfl_xor(ss, m, 64);
            }
            if (li == 0) {
                lnred[w][rb * 16 + lg * 4 + reg][0] = s;
                lnred[w][rb * 16 + lg * 4 + reg][1] = ss;
            }
        }
    __syncthreads();
#pragma unroll
    for (int rb = 0; rb < 2; ++rb)
#pragma unroll
        for (int reg = 0; reg < 4; ++reg) {
            int row = rb * 16 + lg * 4 + reg;
            float s = lnred[0][row][0] + lnred[1][row][0] + lnred[2][row][0] + lnred[3][row][0];
            float ss = lnred[0][row][1] + lnred[1][row][1] + lnred[2][row][1] + lnred[3][row][1];
            float mean = s * (1.0f / 256.0f);
            float var = ss * (1.0f / 256.0f) - mean * mean;
            float rs = rsqrtf(var + 1e-5f);
#pragma unroll
            for (int ctl = 0; ctl < 4; ++ctl) {
                float x = acc2[rb][ctl][reg] + b2v[ctl];
                float v = (x - mean) * rs * g2v[ctl] + be2v[ctl];
                out[(size_t)(rowbase + row) * TOK + w * 64 + ctl * 16 + li] = v;
            }
        }
}

extern "C" void kernel_launch(void* const* d_in, const int* in_sizes, int n_in,
                              void* d_out, int out_size, void* d_ws, size_t ws_size,
                              hipStream_t stream) {
    const float* xyz  = (const float*)d_in[0];
    const float* pf   = (const float*)d_in[1];
    const float* sW1  = (const float*)d_in[2];
    const float* sb1  = (const float*)d_in[3];
    const float* sg1  = (const float*)d_in[4];
    const float* sbe1 = (const float*)d_in[5];
    const float* sW2  = (const float*)d_in[6];
    const float* sb2  = (const float*)d_in[7];
    const float* sg2  = (const float*)d_in[8];
    const float* sbe2 = (const float*)d_in[9];
    const float* tW1  = (const float*)d_in[10];
    const float* tb1  = (const float*)d_in[11];
    const float* tg1  = (const float*)d_in[12];
    const float* tbe1 = (const float*)d_in[13];
    const float* tW2  = (const float*)d_in[14];
    const float* tb2  = (const float*)d_in[15];
    const float* tg2  = (const float*)d_in[16];
    const float* tbe2 = (const float*)d_in[17];

    float* out_tok = (float*)d_out;
    float* out_pc  = out_tok + (size_t)BATCH * NCTR * TOK;

    char* ws = (char*)d_ws;
    int* center_idx = (int*)ws;   ws += (size_t)BATCH * NCTR * 4;
    float* pc_ws    = (float*)ws; ws += (size_t)BATCH * NCTR * 3 * 4;
    int* nbr0       = (int*)ws;   ws += (size_t)BATCH * NCTR * 16 * 4;
    int* nbr1       = (int*)ws;   ws += (size_t)BATCH * NCTR * 32 * 4;
    int* nbr2       = (int*)ws;   ws += (size_t)BATCH * NCTR * 64 * 4;
    float* sf0      = (float*)ws; ws += (size_t)BATCH * NCTR * TOK * 4;
    float* sf1      = (float*)ws; ws += (size_t)BATCH * NCTR * TOK * 4;
    float* sf2      = (float*)ws; ws += (size_t)BATCH * NCTR * TOK * 4;
    const size_t PK1_S  = 16 * 5 * 64 * 16;    // ushorts per scale (sW1)
    const size_t PK2_S  = 16 * 8 * 64 * 16;    // ushorts per scale (sW2)
    const size_t PKT1_S = 16 * 31 * 64 * 16;   // ushorts (tW1)
    const size_t PKT2_S = 16 * 8 * 64 * 16;    // ushorts (tW2)
    unsigned short* pkW1 = (unsigned short*)ws; ws += 3 * PK1_S * 2;
    unsigned short* pkW2 = (unsigned short*)ws; ws += 3 * PK2_S * 2;
    unsigned short* pkT1 = (unsigned short*)ws; ws += PKT1_S * 2;
    unsigned short* pkT2 = (unsigned short*)ws; ws += PKT2_S * 2;
    float* tok_in = (float*)ws;   ws += (size_t)BATCH * NCTR * D_TOK * 4;

    {
        dim3 gp1((16 * 5 * 64 + 255) / 256, 3);
        pack_w<<<gp1, 256, 0, stream>>>(sW1, pkW1, D_IN, 5);
        dim3 gp2((16 * 8 * 64 + 255) / 256, 3);
        pack_w<<<gp2, 256, 0, stream>>>(sW2, pkW2, TOK, 8);
        dim3 gpt1((16 * 31 * 64 + 255) / 256, 1);
        pack_w<<<gpt1, 256, 0, stream>>>(tW1, pkT1, D_TOK, 31);
        dim3 gpt2((16 * 8 * 64 + 255) / 256, 1);
        pack_w<<<gpt2, 256, 0, stream>>>(tW2, pkT2, TOK, 8);
    }

    fps_kernel<<<BATCH, 256, 0, stream>>>(xyz, center_idx, pc_ws, out_pc);

    ballq_kernel<16><<<BATCH * NCTR / 4, 256, 0, stream>>>(xyz, pc_ws, nbr0, (float)(0.1 * 0.1));
    ballq_kernel<32><<<BATCH * NCTR / 4, 256, 0, stream>>>(xyz, pc_ws, nbr1, (float)(0.2 * 0.2));
    ballq_kernel<64><<<BATCH * NCTR / 4, 256, 0, stream>>>(xyz, pc_ws, nbr2, (float)(0.4 * 0.4));

    scale_mfma<16><<<(BATCH * NCTR * 16) / 64, 256, 0, stream>>>(
        xyz, pf, pkW1 + 0 * PK1_S, sb1 + 0 * TOK, sg1 + 0 * TOK, sbe1 + 0 * TOK,
        pkW2 + 0 * PK2_S, sb2 + 0 * TOK, sg2 + 0 * TOK, sbe2 + 0 * TOK,
        nbr0, pc_ws, sf0);
    scale_mfma<32><<<(BATCH * NCTR * 32) / 64, 256, 0, stream>>>(
        xyz, pf, pkW1 + 1 * PK1_S, sb1 + 1 * TOK, sg1 + 1 * TOK, sbe1 + 1 * TOK,
        pkW2 + 1 * PK2_S, sb2 + 1 * TOK, sg2 + 1 * TOK, sbe2 + 1 * TOK,
        nbr1, pc_ws, sf1);
    scale_mfma<64><<<(BATCH * NCTR * 64) / 64, 256, 0, stream>>>(
        xyz, pf, pkW1 + 2 * PK1_S, sb1 + 2 * TOK, sg1 + 2 * TOK, sbe1 + 2 * TOK,
        pkW2 + 2 * PK2_S, sb2 + 2 * TOK, sg2 + 2 * TOK, sbe2 + 2 * TOK,
        nbr2, pc_ws, sf2);

    tok_build<<<BATCH * NCTR, 256, 0, stream>>>(pf, center_idx, pc_ws, sf0, sf1, sf2, tok_in);

    token_mfma<<<(BATCH * NCTR) / 32, 256, 0, stream>>>(
        tok_in, pkT1, tb1, tg1, tbe1, pkT2, tb2, tg2, tbe2, out_tok);
}

// Round 6
// 1634.351 us; speedup vs baseline: 5.0005x; 1.0569x over previous
//
#include <hip/hip_runtime.h>
#include <math.h>

#define BATCH 16
#define NPTS  4096
#define NCTR  512
#define STEM  128
#define TOK   256
#define D_IN  155   // 128 + 3 + 24
#define D_TOK 992   // 128 + 3*256 + 96

typedef short s16x8 __attribute__((ext_vector_type(8)));
typedef float f32x4 __attribute__((ext_vector_type(4)));

// 10000^(-i/15), i=0..15 (token-PE frequencies)
static constexpr float FR15c[16] = {
    1.0f, 0.5411695265464638f, 0.2928644487857941f, 0.15848931670188904f,
    0.08576958626508713f, 0.04641588851809502f, 0.02511886507272720f, 0.01359356392547488f,
    0.007356422487646341f, 0.003981071710586548f, 0.002154434798285365f, 0.001165914465673268f,
    0.0006309573450125754f, 0.0003414548910222948f, 0.0001847849769866168f, 0.0001f};

__device__ __forceinline__ unsigned short f2bf(float f) {
    unsigned u = __float_as_uint(f);
    u += 0x7FFF + ((u >> 16) & 1);
    return (unsigned short)(u >> 16);
}
__device__ __forceinline__ float bf2f(unsigned short b) {
    return __uint_as_float(((unsigned)b) << 16);
}

// split 8 f32 -> hi/lo bf16 fragments via v_cvt_pk_bf16_f32 (RNE)
__device__ __forceinline__ void bsplit8(const float* v, s16x8& hi, s16x8& lo) {
    union { s16x8 s; unsigned w[4]; } H, L;
#pragma unroll
    for (int p = 0; p < 4; ++p) {
        unsigned hp, lp;
        asm("v_cvt_pk_bf16_f32 %0, %1, %2" : "=v"(hp) : "v"(v[2 * p]), "v"(v[2 * p + 1]));
        float r0 = v[2 * p]     - __uint_as_float(hp << 16);
        float r1 = v[2 * p + 1] - __uint_as_float(hp & 0xffff0000u);
        asm("v_cvt_pk_bf16_f32 %0, %1, %2" : "=v"(lp) : "v"(r0), "v"(r1));
        H.w[p] = hp; L.w[p] = lp;
    }
    hi = H.s; lo = L.s;
}

// pack two f32 into two (hi16|lo16) u32 words
__device__ __forceinline__ void pkpair(float v0, float v1, unsigned& w0, unsigned& w1) {
    unsigned hp, lp;
    asm("v_cvt_pk_bf16_f32 %0, %1, %2" : "=v"(hp) : "v"(v0), "v"(v1));
    float r0 = v0 - __uint_as_float(hp << 16);
    float r1 = v1 - __uint_as_float(hp & 0xffff0000u);
    asm("v_cvt_pk_bf16_f32 %0, %1, %2" : "=v"(lp) : "v"(r0), "v"(r1));
    w0 = (hp << 16) | (lp & 0xffffu);
    w1 = (hp & 0xffff0000u) | (lp >> 16);
}

// B-fragment direct load: global (L2-hot) -> VGPR, 16B hi + 16B lo per lane
__device__ __forceinline__ void loadB(const unsigned short* __restrict__ pk,
                                      int frag, int l, s16x8& bh, s16x8& bl) {
    const unsigned short* p = pk + (size_t)frag * 1024 + (size_t)l * 8;
    bh = *(const s16x8*)p;
    bl = *(const s16x8*)(p + 512);
}

// fast exact-GELU: A&S 7.1.26 erf (|abs err| < 2e-7)
__device__ __forceinline__ float gelu_exact(float x) {
    float z = x * 0.70710678118654752f;
    float a = fabsf(z);
    float t = __builtin_amdgcn_rcpf(fmaf(0.3275911f, a, 1.0f));
    float p = fmaf(1.061405429f, t, -1.453152027f);
    p = fmaf(p, t, 1.421413741f);
    p = fmaf(p, t, -0.284496736f);
    p = fmaf(p, t, 0.254829592f);
    p = p * t;
    float e = __expf(-z * z);
    float y = fmaf(-p, e, 1.0f);
    y = (z < 0.0f) ? -y : y;
    return 0.5f * x * (1.0f + y);
}

// exact, non-contracted squared distance to match numpy f32 rounding
__device__ __forceinline__ float sq3(float ax, float ay, float az,
                                     float bx, float by, float bz) {
    float dx = __fsub_rn(ax, bx);
    float dy = __fsub_rn(ay, by);
    float dz = __fsub_rn(az, bz);
    float d = __fmul_rn(dx, dx);
    d = __fadd_rn(d, __fmul_rn(dy, dy));
    d = __fadd_rn(d, __fmul_rn(dz, dz));
    return d;
}

// ---------------- FPS: LDS-resident, 1 barrier/step, no global I/O in loop --
__global__ __launch_bounds__(256) void fps_kernel(const float* __restrict__ xyz,
                                                  int* __restrict__ center_idx,
                                                  float* __restrict__ pc_ws,
                                                  float* __restrict__ pc_out) {
    int b = blockIdx.x;
    int t = threadIdx.x;
    const int w = t >> 6, lane = t & 63;
    const float* X = xyz + (size_t)b * NPTS * 3;
    __shared__ __align__(16) float sxyz[NPTS * 3];  // 48 KB
    __shared__ float swv[2][4];
    __shared__ int   swi[2][4];
    __shared__ int   hist[NCTR];                    // 2 KB
    {
        const float4* src = (const float4*)X;
        float4* dst = (float4*)sxyz;
        for (int i = t; i < NPTS * 3 / 4; i += 256) dst[i] = src[i];
    }
    __syncthreads();
    float px[16], py[16], pz[16], dist[16];
#pragma unroll
    for (int j = 0; j < 16; ++j) {
        int i = t + 256 * j;
        px[j] = sxyz[i * 3 + 0];
        py[j] = sxyz[i * 3 + 1];
        pz[j] = sxyz[i * 3 + 2];
        dist[j] = 1e10f;
    }
    int far = 0;
    for (int s = 0; s < NCTR; ++s) {
        if (t == 0) hist[s] = far;
        float cx = sxyz[far * 3 + 0];
        float cy = sxyz[far * 3 + 1];
        float cz = sxyz[far * 3 + 2];
        float bv = -1.0f;
        int bi = 0;
#pragma unroll
        for (int j = 0; j < 16; ++j) {
            float d = sq3(px[j], py[j], pz[j], cx, cy, cz);
            float nd = fminf(dist[j], d);
            dist[j] = nd;
            if (nd > bv) { bv = nd; bi = t + 256 * j; }  // strictly greater: earliest idx
        }
#pragma unroll
        for (int off = 32; off >= 1; off >>= 1) {
            float ov = __shfl_xor(bv, off, 64);
            int   oi = __shfl_xor(bi, off, 64);
            if (ov > bv || (ov == bv && oi < bi)) { bv = ov; bi = oi; }
        }
        const int p = s & 1;
        if (lane == 0) { swv[p][w] = bv; swi[p][w] = bi; }
        __syncthreads();
        // all threads combine identically (parity dbuf makes next-step writes safe)
        bv = swv[p][0]; bi = swi[p][0];
#pragma unroll
        for (int ww = 1; ww < 4; ++ww) {
            float ov = swv[p][ww]; int oi = swi[p][ww];
            if (ov > bv || (ov == bv && oi < bi)) { bv = ov; bi = oi; }
        }
        far = bi;
    }
    __syncthreads();
    for (int s = t; s < NCTR; s += 256) {
        int idx = hist[s];
        center_idx[b * NCTR + s] = idx;
        float cx = sxyz[idx * 3], cy = sxyz[idx * 3 + 1], cz = sxyz[idx * 3 + 2];
        size_t po = (size_t)(b * NCTR + s) * 3;
        pc_ws[po] = cx; pc_ws[po + 1] = cy; pc_ws[po + 2] = cz;
        pc_out[po] = cx; pc_out[po + 1] = cy; pc_out[po + 2] = cz;
    }
}

// ---------------- Ball query (unchanged) ----------------------------------
template <int K>
__global__ __launch_bounds__(256) void ballq_kernel(const float* __restrict__ xyz,
                                                    const float* __restrict__ pc,
                                                    int* __restrict__ nbr,
                                                    float rr) {
    int cid = blockIdx.x * 4 + (threadIdx.x >> 6);
    int lane = threadIdx.x & 63;
    int b = cid >> 9;
    const float* X = xyz + (size_t)b * NPTS * 3;
    float cx = pc[(size_t)cid * 3 + 0];
    float cy = pc[(size_t)cid * 3 + 1];
    float cz = pc[(size_t)cid * 3 + 2];
    int cnt = 0, first = 0;
    bool have_first = false;
    long long base = (long long)cid * K;
    for (int it = 0; it < NPTS / 64; ++it) {
        int i = it * 64 + lane;
        float d = sq3(cx, cy, cz, X[i * 3], X[i * 3 + 1], X[i * 3 + 2]);
        bool ok = d <= rr;
        unsigned long long mask = __ballot(ok);
        if (!have_first && mask) {
            first = it * 64 + (int)__builtin_ctzll(mask);
            have_first = true;
        }
        int pos = cnt + (int)__popcll(mask & ((1ull << lane) - 1ull));
        if (ok && pos < K) nbr[base + pos] = i;
        cnt += (int)__popcll(mask);
        if (cnt >= K) break;
    }
    int fill = cnt < K ? cnt : K;
    for (int j = fill + lane; j < K; j += 64) nbr[base + j] = first;
}

// ---------------- Weight pack: hi-plane/lo-plane bf16 MFMA B-frags --------
__global__ __launch_bounds__(256) void pack_w(const float* __restrict__ Wbase,
                                              unsigned short* __restrict__ out,
                                              int Kdim, int KS) {
    int s = blockIdx.y;
    const float* W = Wbase + (size_t)s * Kdim * TOK;
    unsigned short* o = out + (size_t)s * 16 * KS * 64 * 16;
    int tid = blockIdx.x * 256 + threadIdx.x;
    if (tid >= 16 * KS * 64) return;
    int lane = tid & 63;
    int frag = tid >> 6;
    int ks = frag % KS;
    int ct = frag / KS;
    int col = ct * 16 + (lane & 15);
    int k0 = ks * 32 + (lane >> 4) * 8;
    unsigned short* hi = o + (size_t)frag * 1024 + lane * 8;
    unsigned short* lo = hi + 512;
#pragma unroll
    for (int j = 0; j < 8; ++j) {
        int k = k0 + j;
        float v = (k < Kdim) ? W[(size_t)k * TOK + col] : 0.0f;
        unsigned short h = f2bf(v);
        hi[j] = h;
        lo[j] = f2bf(v - bf2f(h));
    }
}

// ---------------- Per-scale grouped MLP via bf16x3 MFMA (unchanged) -------
template <int K>
__global__ __launch_bounds__(256, 2) void scale_mfma(
    const float* __restrict__ xyz, const float* __restrict__ pf,
    const unsigned short* __restrict__ pk1, const float* __restrict__ b1,
    const float* __restrict__ g1, const float* __restrict__ be1,
    const unsigned short* __restrict__ pk2, const float* __restrict__ b2,
    const float* __restrict__ g2, const float* __restrict__ be2,
    const int* __restrict__ nbr, const float* __restrict__ pc,
    float* __restrict__ outf) {
    __shared__ unsigned int hpk[64][260];   // 65 KB: full packed-bf16 h
    __shared__ float lnred[4][64][2];       // 2 KB
    const int w = threadIdx.x >> 6, l = threadIdx.x & 63;
    const int lg = l >> 4, li = l & 15;
    const int ws4 = 4 * w;

    int nb[4];
    float relx[4], rely[4], relz[4];
#pragma unroll
    for (int rb = 0; rb < 4; ++rb) {
        int row_g = blockIdx.x * 64 + rb * 16 + li;
        int c = (blockIdx.x * 64 + rb * 16) / K;
        int b = c >> 9;
        int n = nbr[row_g];
        nb[rb] = b * NPTS + n;
        const float* X = xyz + (size_t)nb[rb] * 3;
        const float* C = pc + (size_t)c * 3;
        relx[rb] = __fsub_rn(X[0], C[0]);
        rely[rb] = __fsub_rn(X[1], C[1]);
        relz[rb] = __fsub_rn(X[2], C[2]);
    }

    f32x4 acc1[4][4];
#pragma unroll
    for (int rb = 0; rb < 4; ++rb)
#pragma unroll
        for (int ctl = 0; ctl < 4; ++ctl) acc1[rb][ctl] = (f32x4){0.f, 0.f, 0.f, 0.f};

#pragma unroll
    for (int ks = 0; ks < 5; ++ks) {
        s16x8 Bh[4], Bl[4];
#pragma unroll
        for (int ctl = 0; ctl < 4; ++ctl)
            loadB(pk1, (ws4 + ctl) * 5 + ks, l, Bh[ctl], Bl[ctl]);
        s16x8 Ah[4], Al[4];
#pragma unroll
        for (int rb = 0; rb < 4; ++rb) {
            float v[8];
            if (ks < 4) {
                const float* src = pf + (size_t)nb[rb] * STEM + ks * 32 + lg * 8;
                float4 f0 = *(const float4*)src;
                float4 f1 = *(const float4*)(src + 4);
                v[0] = f0.x; v[1] = f0.y; v[2] = f0.z; v[3] = f0.w;
                v[4] = f1.x; v[5] = f1.y; v[6] = f1.z; v[7] = f1.w;
            } else {
#pragma unroll
                for (int j = 0; j < 8; ++j) {
                    int ch = lg * 8 + j;
                    float val = 0.0f;
                    if (ch < 3) {
                        val = (ch == 0) ? relx[rb] : ((ch == 1) ? rely[rb] : relz[rb]);
                    } else if (ch < 27) {
                        int rem = ch - 3;
                        int axis = rem >> 3, r8 = rem & 7;
                        int fi = (r8 < 4) ? r8 : r8 - 4;
                        float fr = (fi == 0) ? 1.0f
                                  : (fi == 1) ? 0.046415888336127795f
                                  : (fi == 2) ? 0.0021544346900318843f : 1e-4f;
                        float rl = (axis == 0) ? relx[rb] : ((axis == 1) ? rely[rb] : relz[rb]);
                        float ang = rl * fr;
                        val = (r8 < 4) ? __sinf(ang) : __cosf(ang);
                    }
                    v[j] = val;
                }
            }
            bsplit8(v, Ah[rb], Al[rb]);
        }
#pragma unroll
        for (int ctl = 0; ctl < 4; ++ctl)
#pragma unroll
            for (int rb = 0; rb < 4; ++rb) {
                acc1[rb][ctl] = __builtin_amdgcn_mfma_f32_16x16x32_bf16(Ah[rb], Bh[ctl], acc1[rb][ctl], 0, 0, 0);
                acc1[rb][ctl] = __builtin_amdgcn_mfma_f32_16x16x32_bf16(Ah[rb], Bl[ctl], acc1[rb][ctl], 0, 0, 0);
                acc1[rb][ctl] = __builtin_amdgcn_mfma_f32_16x16x32_bf16(Al[rb], Bh[ctl], acc1[rb][ctl], 0, 0, 0);
            }
    }

    {
        float b1v[4], g1v[4], be1v[4];
#pragma unroll
        for (int ctl = 0; ctl < 4; ++ctl) {
            int col = w * 64 + ctl * 16 + li;
            b1v[ctl] = b1[col]; g1v[ctl] = g1[col]; be1v[ctl] = be1[col];
        }
#pragma unroll
        for (int rb = 0; rb < 4; ++rb)
#pragma unroll
            for (int reg = 0; reg < 4; ++reg) {
                float s = 0.f, ss = 0.f;
#pragma unroll
                for (int ctl = 0; ctl < 4; ++ctl) {
                    float x = acc1[rb][ctl][reg] + b1v[ctl];
                    s += x; ss = fmaf(x, x, ss);
                }
#pragma unroll
                for (int m = 1; m <= 8; m <<= 1) {
                    s += __shfl_xor(s, m, 64);
                    ss += __shfl_xor(ss, m, 64);
                }
                if (li == 0) {
                    lnred[w][rb * 16 + lg * 4 + reg][0] = s;
                    lnred[w][rb * 16 + lg * 4 + reg][1] = ss;
                }
            }
        __syncthreads();  // B1
#pragma unroll
        for (int rb = 0; rb < 4; ++rb)
#pragma unroll
            for (int reg = 0; reg < 4; ++reg) {
                int row = rb * 16 + lg * 4 + reg;
                float s = lnred[0][row][0] + lnred[1][row][0] + lnred[2][row][0] + lnred[3][row][0];
                float ss = lnred[0][row][1] + lnred[1][row][1] + lnred[2][row][1] + lnred[3][row][1];
                float mean = s * (1.0f / 256.0f);
                float var = ss * (1.0f / 256.0f) - mean * mean;
                float rs = rsqrtf(var + 1e-5f);
#pragma unroll
                for (int ctl = 0; ctl < 4; ++ctl) {
                    float x = acc1[rb][ctl][reg] + b1v[ctl];
                    acc1[rb][ctl][reg] = gelu_exact((x - mean) * rs * g1v[ctl] + be1v[ctl]);
                }
            }
    }

#pragma unroll
    for (int rb = 0; rb < 4; ++rb)
#pragma unroll
        for (int ctl = 0; ctl < 4; ++ctl) {
            unsigned w0, w1, w2, w3;
            pkpair(acc1[rb][ctl][0], acc1[rb][ctl][1], w0, w1);
            pkpair(acc1[rb][ctl][2], acc1[rb][ctl][3], w2, w3);
            int r0 = rb * 16 + lg * 4;
            int kc = w * 64 + ctl * 16 + li;
            hpk[r0 + 0][kc] = w0; hpk[r0 + 1][kc] = w1;
            hpk[r0 + 2][kc] = w2; hpk[r0 + 3][kc] = w3;
        }
    __syncthreads();  // B2

    f32x4 acc2[4][4];
#pragma unroll
    for (int rb = 0; rb < 4; ++rb)
#pragma unroll
        for (int ctl = 0; ctl < 4; ++ctl) acc2[rb][ctl] = (f32x4){0.f, 0.f, 0.f, 0.f};

#pragma unroll
    for (int q = 0; q < 8; ++q) {
        s16x8 Bh[4], Bl[4];
#pragma unroll
        for (int ctl = 0; ctl < 4; ++ctl)
            loadB(pk2, (ws4 + ctl) * 8 + q, l, Bh[ctl], Bl[ctl]);
#pragma unroll
        for (int rb = 0; rb < 4; ++rb) {
            const unsigned int* hp = &hpk[rb * 16 + li][q * 32 + lg * 8];
            int4 xa = *(const int4*)hp;
            int4 xb = *(const int4*)(hp + 4);
            unsigned x[8] = {(unsigned)xa.x, (unsigned)xa.y, (unsigned)xa.z, (unsigned)xa.w,
                             (unsigned)xb.x, (unsigned)xb.y, (unsigned)xb.z, (unsigned)xb.w};
            union { s16x8 s; unsigned w[4]; } H, L;
#pragma unroll
            for (int p = 0; p < 4; ++p) {
                H.w[p] = (x[2 * p] >> 16) | (x[2 * p + 1] & 0xffff0000u);
                L.w[p] = (x[2 * p] & 0xffffu) | (x[2 * p + 1] << 16);
            }
#pragma unroll
            for (int ctl = 0; ctl < 4; ++ctl) {
                acc2[rb][ctl] = __builtin_amdgcn_mfma_f32_16x16x32_bf16(H.s, Bh[ctl], acc2[rb][ctl], 0, 0, 0);
                acc2[rb][ctl] = __builtin_amdgcn_mfma_f32_16x16x32_bf16(H.s, Bl[ctl], acc2[rb][ctl], 0, 0, 0);
                acc2[rb][ctl] = __builtin_amdgcn_mfma_f32_16x16x32_bf16(L.s, Bh[ctl], acc2[rb][ctl], 0, 0, 0);
            }
        }
    }

    float b2v[4], g2v[4], be2v[4];
#pragma unroll
    for (int ctl = 0; ctl < 4; ++ctl) {
        int col = w * 64 + ctl * 16 + li;
        b2v[ctl] = b2[col]; g2v[ctl] = g2[col]; be2v[ctl] = be2[col];
    }
#pragma unroll
    for (int rb = 0; rb < 4; ++rb)
#pragma unroll
        for (int reg = 0; reg < 4; ++reg) {
            float s = 0.f, ss = 0.f;
#pragma unroll
            for (int ctl = 0; ctl < 4; ++ctl) {
                float x = acc2[rb][ctl][reg] + b2v[ctl];
                s += x; ss = fmaf(x, x, ss);
            }
#pragma unroll
            for (int m = 1; m <= 8; m <<= 1) {
                s += __shfl_xor(s, m, 64);
                ss += __shfl_xor(ss, m, 64);
            }
            if (li == 0) {
                lnred[w][rb * 16 + lg * 4 + reg][0] = s;
                lnred[w][rb * 16 + lg * 4 + reg][1] = ss;
            }
        }
    __syncthreads();  // B3
#pragma unroll
    for (int rb = 0; rb < 4; ++rb)
#pragma unroll
        for (int reg = 0; reg < 4; ++reg) {
            int row = rb * 16 + lg * 4 + reg;
            float s = lnred[0][row][0] + lnred[1][row][0] + lnred[2][row][0] + lnred[3][row][0];
            float ss = lnred[0][row][1] + lnred[1][row][1] + lnred[2][row][1] + lnred[3][row][1];
            float mean = s * (1.0f / 256.0f);
            float var = ss * (1.0f / 256.0f) - mean * mean;
            float rs = rsqrtf(var + 1e-5f);
#pragma unroll
            for (int ctl = 0; ctl < 4; ++ctl) {
                float x = acc2[rb][ctl][reg] + b2v[ctl];
                acc2[rb][ctl][reg] = (x - mean) * rs * g2v[ctl] + be2v[ctl];
            }
        }

    const int CPB = 64 / K;
    const int RBC = K / 16;
#pragma unroll
    for (int cg = 0; cg < CPB; ++cg)
#pragma unroll
        for (int ctl = 0; ctl < 4; ++ctl) {
            float mx = -3.4e38f;
#pragma unroll
            for (int rbl = 0; rbl < RBC; ++rbl) {
                int rb = cg * RBC + rbl;
#pragma unroll
                for (int reg = 0; reg < 4; ++reg) mx = fmaxf(mx, acc2[rb][ctl][reg]);
            }
            mx = fmaxf(mx, __shfl_xor(mx, 16, 64));
            mx = fmaxf(mx, __shfl_xor(mx, 32, 64));
            if (lg == 0)
                outf[(size_t)(blockIdx.x * CPB + cg) * TOK + w * 64 + ctl * 16 + li] = mx;
        }
}

// ---------------- Token MLP via bf16x3 MFMA, tok_in built on the fly -------
// Each 32-col k-chunk lies entirely in one segment:
//  ks 0..3: pf[center]; 4..11: sf0; 12..19: sf1; 20..27: sf2; 28..30: PE.
__global__ __launch_bounds__(256, 2) void token_mfma(
    const float* __restrict__ pf, const int* __restrict__ center_idx,
    const float* __restrict__ pc, const float* __restrict__ sf0,
    const float* __restrict__ sf1, const float* __restrict__ sf2,
    const unsigned short* __restrict__ pk1, const float* __restrict__ b1,
    const float* __restrict__ g1, const float* __restrict__ be1,
    const unsigned short* __restrict__ pk2, const float* __restrict__ b2,
    const float* __restrict__ g2, const float* __restrict__ be2,
    float* __restrict__ out) {
    __shared__ unsigned int hpk[32][260];
    __shared__ float lnred[4][32][2];
    const int w = threadIdx.x >> 6, l = threadIdx.x & 63;
    const int lg = l >> 4, li = l & 15;
    const int ws4 = 4 * w;
    const int rowbase = blockIdx.x * 32;

    int rowg[2];
    const float* pfc[2];
    float pcx[2], pcy[2], pcz[2];
#pragma unroll
    for (int rb = 0; rb < 2; ++rb) {
        int row = rowbase + rb * 16 + li;
        rowg[rb] = row;
        int b = row >> 9;
        int cidx = center_idx[row];
        pfc[rb] = pf + ((size_t)b * NPTS + cidx) * STEM;
        pcx[rb] = pc[(size_t)row * 3 + 0];
        pcy[rb] = pc[(size_t)row * 3 + 1];
        pcz[rb] = pc[(size_t)row * 3 + 2];
    }

    f32x4 acc1[2][4];
#pragma unroll
    for (int rb = 0; rb < 2; ++rb)
#pragma unroll
        for (int ctl = 0; ctl < 4; ++ctl) acc1[rb][ctl] = (f32x4){0.f, 0.f, 0.f, 0.f};

#pragma unroll 2
    for (int ks = 0; ks < 31; ++ks) {
        s16x8 Bh[4], Bl[4];
#pragma unroll
        for (int ctl = 0; ctl < 4; ++ctl)
            loadB(pk1, (ws4 + ctl) * 31 + ks, l, Bh[ctl], Bl[ctl]);
        s16x8 Ah[2], Al[2];
#pragma unroll
        for (int rb = 0; rb < 2; ++rb) {
            float v[8];
            if (ks < 28) {
                const float* src;
                if (ks < 4)       src = pfc[rb] + ks * 32 + lg * 8;
                else if (ks < 12) src = sf0 + (size_t)rowg[rb] * TOK + (ks - 4) * 32 + lg * 8;
                else if (ks < 20) src = sf1 + (size_t)rowg[rb] * TOK + (ks - 12) * 32 + lg * 8;
                else              src = sf2 + (size_t)rowg[rb] * TOK + (ks - 20) * 32 + lg * 8;
                float4 f0 = *(const float4*)src;
                float4 f1 = *(const float4*)(src + 4);
                v[0] = f0.x; v[1] = f0.y; v[2] = f0.z; v[3] = f0.w;
                v[4] = f1.x; v[5] = f1.y; v[6] = f1.z; v[7] = f1.w;
            } else {
                float c = (ks == 28) ? pcx[rb] : ((ks == 29) ? pcy[rb] : pcz[rb]);
#pragma unroll
                for (int j = 0; j < 8; ++j) {
                    float fr = (lg & 1) ? FR15c[8 + j] : FR15c[j];
                    float ang = c * fr;
                    v[j] = (lg < 2) ? __sinf(ang) : __cosf(ang);
                }
            }
            bsplit8(v, Ah[rb], Al[rb]);
        }
#pragma unroll
        for (int ctl = 0; ctl < 4; ++ctl)
#pragma unroll
            for (int rb = 0; rb < 2; ++rb) {
                acc1[rb][ctl] = __builtin_amdgcn_mfma_f32_16x16x32_bf16(Ah[rb], Bh[ctl], acc1[rb][ctl], 0, 0, 0);
                acc1[rb][ctl] = __builtin_amdgcn_mfma_f32_16x16x32_bf16(Ah[rb], Bl[ctl], acc1[rb][ctl], 0, 0, 0);
                acc1[rb][ctl] = __builtin_amdgcn_mfma_f32_16x16x32_bf16(Al[rb], Bh[ctl], acc1[rb][ctl], 0, 0, 0);
            }
    }

    {
        float b1v[4], g1v[4], be1v[4];
#pragma unroll
        for (int ctl = 0; ctl < 4; ++ctl) {
            int col = w * 64 + ctl * 16 + li;
            b1v[ctl] = b1[col]; g1v[ctl] = g1[col]; be1v[ctl] = be1[col];
        }
#pragma unroll
        for (int rb = 0; rb < 2; ++rb)
#pragma unroll
            for (int reg = 0; reg < 4; ++reg) {
                float s = 0.f, ss = 0.f;
#pragma unroll
                for (int ctl = 0; ctl < 4; ++ctl) {
                    float x = acc1[rb][ctl][reg] + b1v[ctl];
                    s += x; ss = fmaf(x, x, ss);
                }
#pragma unroll
                for (int m = 1; m <= 8; m <<= 1) {
                    s += __shfl_xor(s, m, 64);
                    ss += __shfl_xor(ss, m, 64);
                }
                if (li == 0) {
                    lnred[w][rb * 16 + lg * 4 + reg][0] = s;
                    lnred[w][rb * 16 + lg * 4 + reg][1] = ss;
                }
            }
        __syncthreads();
#pragma unroll
        for (int rb = 0; rb < 2; ++rb)
#pragma unroll
            for (int reg = 0; reg < 4; ++reg) {
                int row = rb * 16 + lg * 4 + reg;
                float s = lnred[0][row][0] + lnred[1][row][0] + lnred[2][row][0] + lnred[3][row][0];
                float ss = lnred[0][row][1] + lnred[1][row][1] + lnred[2][row][1] + lnred[3][row][1];
                float mean = s * (1.0f / 256.0f);
                float var = ss * (1.0f / 256.0f) - mean * mean;
                float rs = rsqrtf(var + 1e-5f);
#pragma unroll
                for (int ctl = 0; ctl < 4; ++ctl) {
                    float x = acc1[rb][ctl][reg] + b1v[ctl];
                    acc1[rb][ctl][reg] = gelu_exact((x - mean) * rs * g1v[ctl] + be1v[ctl]);
                }
            }
    }

#pragma unroll
    for (int rb = 0; rb < 2; ++rb)
#pragma unroll
        for (int ctl = 0; ctl < 4; ++ctl) {
            unsigned w0, w1, w2, w3;
            pkpair(acc1[rb][ctl][0], acc1[rb][ctl][1], w0, w1);
            pkpair(acc1[rb][ctl][2], acc1[rb][ctl][3], w2, w3);
            int r0 = rb * 16 + lg * 4;
            int kc = w * 64 + ctl * 16 + li;
            hpk[r0 + 0][kc] = w0; hpk[r0 + 1][kc] = w1;
            hpk[r0 + 2][kc] = w2; hpk[r0 + 3][kc] = w3;
        }
    __syncthreads();

    f32x4 acc2[2][4];
#pragma unroll
    for (int rb = 0; rb < 2; ++rb)
#pragma unroll
        for (int ctl = 0; ctl < 4; ++ctl) acc2[rb][ctl] = (f32x4){0.f, 0.f, 0.f, 0.f};
#pragma unroll
    for (int q = 0; q < 8; ++q) {
        s16x8 Bh[4], Bl[4];
#pragma unroll
        for (int ctl = 0; ctl < 4; ++ctl)
            loadB(pk2, (ws4 + ctl) * 8 + q, l, Bh[ctl], Bl[ctl]);
#pragma unroll
        for (int rb = 0; rb < 2; ++rb) {
            const unsigned int* hp = &hpk[rb * 16 + li][q * 32 + lg * 8];
            int4 xa = *(const int4*)hp;
            int4 xb = *(const int4*)(hp + 4);
            unsigned x[8] = {(unsigned)xa.x, (unsigned)xa.y, (unsigned)xa.z, (unsigned)xa.w,
                             (unsigned)xb.x, (unsigned)xb.y, (unsigned)xb.z, (unsigned)xb.w};
            union { s16x8 s; unsigned w[4]; } H, L;
#pragma unroll
            for (int p = 0; p < 4; ++p) {
                H.w[p] = (x[2 * p] >> 16) | (x[2 * p + 1] & 0xffff0000u);
                L.w[p] = (x[2 * p] & 0xffffu) | (x[2 * p + 1] << 16);
            }
#pragma unroll
            for (int ctl = 0; ctl < 4; ++ctl) {
                acc2[rb][ctl] = __builtin_amdgcn_mfma_f32_16x16x32_bf16(H.s, Bh[ctl], acc2[rb][ctl], 0, 0, 0);
                acc2[rb][ctl] = __builtin_amdgcn_mfma_f32_16x16x32_bf16(H.s, Bl[ctl], acc2[rb][ctl], 0, 0, 0);
                acc2[rb][ctl] = __builtin_amdgcn_mfma_f32_16x16x32_bf16(L.s, Bh[ctl], acc2[rb][ctl], 0, 0, 0);
            }
        }
    }

    float b2v[4], g2v[4], be2v[4];
#pragma unroll
    for (int ctl = 0; ctl < 4; ++ctl) {
        int col = w * 64 + ctl * 16 + li;
        b2v[ctl] = b2[col]; g2v[ctl] = g2[col]; be2v[ctl] = be2[col];
    }
#pragma unroll
    for (int rb = 0; rb < 2; ++rb)
#pragma unroll
        for (int reg = 0; reg < 4; ++reg) {
            float s = 0.f, ss = 0.f;
#pragma unroll
            for (int ctl = 0; ctl < 4; ++ctl) {
                float x = acc2[rb][ctl][reg] + b2v[ctl];
                s += x; ss = fmaf(x, x, ss);
            }
#pragma unroll
            for (int m = 1; m <= 8; m <<= 1) {
                s += __shfl_xor(s, m, 64);
                ss += __shfl_xor(ss, m, 64);
            }
            if (li == 0) {
                lnred[w][rb * 16 + lg * 4 + reg][0] = s;
                lnred[w][rb * 16 + lg * 4 + reg][1] = ss;
            }
        }
    __syncthreads();
#pragma unroll
    for (int rb = 0; rb < 2; ++rb)
#pragma unroll
        for (int reg = 0; reg < 4; ++reg) {
            int row = rb * 16 + lg * 4 + reg;
            float s = lnred[0][row][0] + lnred[1][row][0] + lnred[2][row][0] + lnred[3][row][0];
            float ss = lnred[0][row][1] + lnred[1][row][1] + lnred[2][row][1] + lnred[3][row][1];
            float mean = s * (1.0f / 256.0f);
            float var = ss * (1.0f / 256.0f) - mean * mean;
            float rs = rsqrtf(var + 1e-5f);
#pragma unroll
            for (int ctl = 0; ctl < 4; ++ctl) {
                float x = acc2[rb][ctl][reg] + b2v[ctl];
                float v = (x - mean) * rs * g2v[ctl] + be2v[ctl];
                out[(size_t)(rowbase + row) * TOK + w * 64 + ctl * 16 + li] = v;
            }
        }
}

extern "C" void kernel_launch(void* const* d_in, const int* in_sizes, int n_in,
                              void* d_out, int out_size, void* d_ws, size_t ws_size,
                              hipStream_t stream) {
    const float* xyz  = (const float*)d_in[0];
    const float* pf   = (const float*)d_in[1];
    const float* sW1  = (const float*)d_in[2];
    const float* sb1  = (const float*)d_in[3];
    const float* sg1  = (const float*)d_in[4];
    const float* sbe1 = (const float*)d_in[5];
    const float* sW2  = (const float*)d_in[6];
    const float* sb2  = (const float*)d_in[7];
    const float* sg2  = (const float*)d_in[8];
    const float* sbe2 = (const float*)d_in[9];
    const float* tW1  = (const float*)d_in[10];
    const float* tb1  = (const float*)d_in[11];
    const float* tg1  = (const float*)d_in[12];
    const float* tbe1 = (const float*)d_in[13];
    const float* tW2  = (const float*)d_in[14];
    const float* tb2  = (const float*)d_in[15];
    const float* tg2  = (const float*)d_in[16];
    const float* tbe2 = (const float*)d_in[17];

    float* out_tok = (float*)d_out;
    float* out_pc  = out_tok + (size_t)BATCH * NCTR * TOK;

    char* ws = (char*)d_ws;
    int* center_idx = (int*)ws;   ws += (size_t)BATCH * NCTR * 4;
    float* pc_ws    = (float*)ws; ws += (size_t)BATCH * NCTR * 3 * 4;
    int* nbr0       = (int*)ws;   ws += (size_t)BATCH * NCTR * 16 * 4;
    int* nbr1       = (int*)ws;   ws += (size_t)BATCH * NCTR * 32 * 4;
    int* nbr2       = (int*)ws;   ws += (size_t)BATCH * NCTR * 64 * 4;
    float* sf0      = (float*)ws; ws += (size_t)BATCH * NCTR * TOK * 4;
    float* sf1      = (float*)ws; ws += (size_t)BATCH * NCTR * TOK * 4;
    float* sf2      = (float*)ws; ws += (size_t)BATCH * NCTR * TOK * 4;
    const size_t PK1_S  = 16 * 5 * 64 * 16;    // ushorts per scale (sW1)
    const size_t PK2_S  = 16 * 8 * 64 * 16;    // ushorts per scale (sW2)
    const size_t PKT1_S = 16 * 31 * 64 * 16;   // ushorts (tW1)
    const size_t PKT2_S = 16 * 8 * 64 * 16;    // ushorts (tW2)
    unsigned short* pkW1 = (unsigned short*)ws; ws += 3 * PK1_S * 2;
    unsigned short* pkW2 = (unsigned short*)ws; ws += 3 * PK2_S * 2;
    unsigned short* pkT1 = (unsigned short*)ws; ws += PKT1_S * 2;
    unsigned short* pkT2 = (unsigned short*)ws; ws += PKT2_S * 2;

    {
        dim3 gp1((16 * 5 * 64 + 255) / 256, 3);
        pack_w<<<gp1, 256, 0, stream>>>(sW1, pkW1, D_IN, 5);
        dim3 gp2((16 * 8 * 64 + 255) / 256, 3);
        pack_w<<<gp2, 256, 0, stream>>>(sW2, pkW2, TOK, 8);
        dim3 gpt1((16 * 31 * 64 + 255) / 256, 1);
        pack_w<<<gpt1, 256, 0, stream>>>(tW1, pkT1, D_TOK, 31);
        dim3 gpt2((16 * 8 * 64 + 255) / 256, 1);
        pack_w<<<gpt2, 256, 0, stream>>>(tW2, pkT2, TOK, 8);
    }

    fps_kernel<<<BATCH, 256, 0, stream>>>(xyz, center_idx, pc_ws, out_pc);

    ballq_kernel<16><<<BATCH * NCTR / 4, 256, 0, stream>>>(xyz, pc_ws, nbr0, (float)(0.1 * 0.1));
    ballq_kernel<32><<<BATCH * NCTR / 4, 256, 0, stream>>>(xyz, pc_ws, nbr1, (float)(0.2 * 0.2));
    ballq_kernel<64><<<BATCH * NCTR / 4, 256, 0, stream>>>(xyz, pc_ws, nbr2, (float)(0.4 * 0.4));

    scale_mfma<16><<<(BATCH * NCTR * 16) / 64, 256, 0, stream>>>(
        xyz, pf, pkW1 + 0 * PK1_S, sb1 + 0 * TOK, sg1 + 0 * TOK, sbe1 + 0 * TOK,
        pkW2 + 0 * PK2_S, sb2 + 0 * TOK, sg2 + 0 * TOK, sbe2 + 0 * TOK,
        nbr0, pc_ws, sf0);
    scale_mfma<32><<<(BATCH * NCTR * 32) / 64, 256, 0, stream>>>(
        xyz, pf, pkW1 + 1 * PK1_S, sb1 + 1 * TOK, sg1 + 1 * TOK, sbe1 + 1 * TOK,
        pkW2 + 1 * PK2_S, sb2 + 1 * TOK, sg2 + 1 * TOK, sbe2 + 1 * TOK,
        nbr1, pc_ws, sf1);
    scale_mfma<64><<<(BATCH * NCTR * 64) / 64, 256, 0, stream>>>(
        xyz, pf, pkW1 + 2 * PK1_S, sb1 + 2 * TOK, sg1 + 2 * TOK, sbe1 + 2 * TOK,
        pkW2 + 2 * PK2_S, sb2 + 2 * TOK, sg2 + 2 * TOK, sbe2 + 2 * TOK,
        nbr2, pc_ws, sf2);

    token_mfma<<<(BATCH * NCTR) / 32, 256, 0, stream>>>(
        pf, center_idx, pc_ws, sf0, sf1, sf2,
        pkT1, tb1, tg1, tbe1, pkT2, tb2, tg2, tbe2, out_tok);
}